// Round 14
// baseline (304.639 us; speedup 1.0000x reference)
//
#include <hip/hip_runtime.h>
#include <hip/hip_bf16.h>
#include <math.h>

// ---------------------------------------------------------------------------
// EncoderLayer, bf16-MFMA mixed precision for MI355X (gfx950).
// B=8, S=2048, D=512, H=8, DK=64, DFF=2048, M=16384.
// Round-14: attention VALU trims on the r13 swapped-QK structure:
//  (1) loop-invariant zero C-operand for QK MFMAs (kills 32 movs/tile),
//  (2) row-sum via MFMA-with-ones into lacc (kills 32 adds/tile + the
//      final permlane/shfl combine; invr=1/lacc[r] is reg-aligned with O),
//  (3) cross-half pmax combine moved inside the rare rescale branch.
// GEMM/LN/pack byte-identical to round 13.
// ---------------------------------------------------------------------------

#define D_MODEL 512
#define NHEAD   8
#define DKH     64
#define SEQ     2048
#define BATCH   8
#define DFF     2048
#define MROWS   (BATCH * SEQ)          // 16384
#define QKVLD   1536                   // fused q|k|v row stride

typedef __bf16 bf16x8 __attribute__((ext_vector_type(8)));
typedef float  f32x4  __attribute__((ext_vector_type(4)));
typedef float  f32x16 __attribute__((ext_vector_type(16)));

__device__ __forceinline__ unsigned short f2bf(float f) {
    union { float f; unsigned u; } v; v.f = f;
    return (unsigned short)((v.u + 0x7FFFu + ((v.u >> 16) & 1u)) >> 16);
}

__device__ __forceinline__ float bf2f(unsigned short u) {
    union { unsigned u; float f; } v; v.u = (unsigned)u << 16;
    return v.f;
}

__device__ __forceinline__ unsigned cvtpk(float a, float b) {   // bf16(a)|bf16(b)<<16
    unsigned r;
    asm("v_cvt_pk_bf16_f32 %0, %1, %2" : "=v"(r) : "v"(a), "v"(b));
    return r;
}

__device__ __forceinline__ float fexp2(float x) {   // raw v_exp_f32 (2^x)
    float r; asm("v_exp_f32 %0, %1" : "=v"(r) : "v"(x)); return r;
}

// v_permlane32_swap_b32: x<-[x(0:31)|y(0:31)], y<-[x(32:63)|y(32:63)]
__device__ __forceinline__ void plswap(unsigned& x, unsigned& y) {
    asm volatile("v_permlane32_swap_b32 %0, %1" : "+v"(x), "+v"(y));
}

__device__ __forceinline__ unsigned fbits(float f) {
    union { float f; unsigned u; } v; v.f = f; return v.u;
}
__device__ __forceinline__ float bitsf(unsigned u) {
    union { unsigned u; float f; } v; v.u = u; return v.f;
}

__device__ __forceinline__ f32x4 mfma16(bf16x8 a, bf16x8 b, f32x4 c) {
    return __builtin_amdgcn_mfma_f32_16x16x32_bf16(a, b, c, 0, 0, 0);
}
__device__ __forceinline__ f32x16 mfma32(bf16x8 a, bf16x8 b, f32x16 c) {
    return __builtin_amdgcn_mfma_f32_32x32x16_bf16(a, b, c, 0, 0, 0);
}

// async global -> LDS, 16 B per lane; lds base must be wave-uniform
__device__ __forceinline__ void gld_lds16(const unsigned short* g, unsigned short* l) {
    __builtin_amdgcn_global_load_lds(
        (const __attribute__((address_space(1))) unsigned int*)g,
        (__attribute__((address_space(3))) unsigned int*)l, 16, 0, 0);
}

// ---------------------------------------------------------------------------
// bf16 MFMA GEMM (unchanged from round 12): 128x128 tile, BK=32, 4 waves,
// double-buffered global_load_lds staging. RESMODE: 0 none, 1 fp32, 2 bf16.
// ---------------------------------------------------------------------------
template<bool BIAS, bool RELU, int RESMODE, bool OUTF32>
__global__ __launch_bounds__(256)
void mfma_gemm(const unsigned short* __restrict__ Av,
               const unsigned short* __restrict__ Bt,
               const float* __restrict__ bias, const void* __restrict__ resv,
               void* __restrict__ Cv, int Kdim, int lda, int ldc)
{
    __shared__ unsigned short As[2][128][32];
    __shared__ unsigned short Bs[2][128][32];

    const int tid  = threadIdx.x;
    const int lane = tid & 63;
    const int w    = tid >> 6;
    const int mq   = (w >> 1) << 6;
    const int nq   = (w & 1) << 6;
    const int lrow = lane & 15;
    const int g    = lane >> 4;
    const int lk   = g << 3;

    const int row0 = blockIdx.y << 7;
    const int col0 = blockIdx.x << 7;

    const int c0   = w << 5;
    const int srow = lane >> 2;
    const int scol = (lane & 3) << 3;
    const size_t aoff = (size_t)(row0 + c0 + srow) * lda  + scol;
    const size_t boff = (size_t)(col0 + c0 + srow) * Kdim + scol;

    auto stage = [&](int buf, int kt) {
        gld_lds16(Av + aoff + kt,                        &As[buf][c0     ][0]);
        gld_lds16(Av + aoff + (size_t)16 * lda  + kt,    &As[buf][c0 + 16][0]);
        gld_lds16(Bt + boff + kt,                        &Bs[buf][c0     ][0]);
        gld_lds16(Bt + boff + (size_t)16 * Kdim + kt,    &Bs[buf][c0 + 16][0]);
    };

    const f32x4 zero = {0.f, 0.f, 0.f, 0.f};
    f32x4 acc[4][4];
    #pragma unroll
    for (int i = 0; i < 4; ++i)
        #pragma unroll
        for (int j = 0; j < 4; ++j) acc[i][j] = zero;

    stage(0, 0);
    __syncthreads();

    int cur = 0;
    for (int kt = 0; kt < Kdim; kt += 32) {
        if (kt + 32 < Kdim) stage(cur ^ 1, kt + 32);

        bf16x8 af[4], bfv[4];
        #pragma unroll
        for (int mf = 0; mf < 4; ++mf)
            af[mf] = *(const bf16x8*)&As[cur][mq + mf * 16 + lrow][lk];
        #pragma unroll
        for (int nf = 0; nf < 4; ++nf)
            bfv[nf] = *(const bf16x8*)&Bs[cur][nq + nf * 16 + lrow][lk];
        #pragma unroll
        for (int mf = 0; mf < 4; ++mf)
            #pragma unroll
            for (int nf = 0; nf < 4; ++nf)
                acc[mf][nf] = mfma16(af[mf], bfv[nf], acc[mf][nf]);

        __syncthreads();
        cur ^= 1;
    }

    const int orow = row0 + mq + g * 4;
    const int ocol = col0 + nq + lrow;
    #pragma unroll
    for (int mf = 0; mf < 4; ++mf) {
        #pragma unroll
        for (int nf = 0; nf < 4; ++nf) {
            const int cc = ocol + nf * 16;
            float bv = 0.f;
            if constexpr (BIAS) bv = bias[cc];
            float v[4];
            #pragma unroll
            for (int r = 0; r < 4; ++r) {
                const int rr = orow + mf * 16 + r;
                v[r] = acc[mf][nf][r];
                if constexpr (BIAS) v[r] += bv;
                if constexpr (RELU) v[r] = fmaxf(v[r], 0.f);
                if constexpr (RESMODE == 1)
                    v[r] += ((const float*)resv)[(size_t)rr * ldc + cc];
                if constexpr (RESMODE == 2)
                    v[r] += bf2f(((const unsigned short*)resv)[(size_t)rr * ldc + cc]);
                if constexpr (OUTF32) ((float*)Cv)[(size_t)rr * ldc + cc] = v[r];
            }
            if constexpr (!OUTF32) {
                const unsigned u01 = cvtpk(v[0], v[1]);
                const unsigned u23 = cvtpk(v[2], v[3]);
                unsigned short* cp = (unsigned short*)Cv + (size_t)(orow + mf * 16) * ldc + cc;
                cp[0]                 = (unsigned short)u01;
                cp[(size_t)ldc]       = (unsigned short)(u01 >> 16);
                cp[(size_t)ldc * 2]   = (unsigned short)u23;
                cp[(size_t)ldc * 3]   = (unsigned short)(u23 >> 16);
            }
        }
    }
}

// ---------------------------------------------------------------------------
// Flash attention v7 (swapped QK^T, 32x32x16 MFMA, in-register P, MFMA
// row-sum): 8 waves x 32 q-rows, 512 blocks, KV tiles of 64 double-buffered
// (single barrier/tile). Lane owns q = lane&31; h = lane>>5 is the kv half.
// QK accumulators start from a loop-invariant zero C-operand (no per-tile
// movs). Row sums accumulate via mfma32(pa, ones, lacc) -- lacc[r] is the
// full row sum for q-row (r&3)+8*(r>>2)+4h, register-aligned with oacc.
// ---------------------------------------------------------------------------
__global__ __launch_bounds__(512, 4)
void mfma_attn(unsigned short* __restrict__ qkv)
{
    __shared__ unsigned short Ks[2][64][72];   // K tile [buf][kv][dk]
    __shared__ unsigned short Vt[2][64][72];   // V transposed [buf][dk][kv]

    const int tid  = threadIdx.x;
    const int lane = tid & 63;
    const int w    = tid >> 6;
    const int q32  = lane & 31;      // this lane's q (and kv-row selector)
    const int h    = lane >> 5;      // kv half / k-chunk selector

    // XCD swizzle: 512 blocks = 8 xcd x (8 bh-groups x 8 q-tiles)
    const int bid  = blockIdx.x;
    const int idx  = bid >> 3;
    const int bh   = (bid & 7) * 8 + (idx & 7);
    const int b  = bh >> 3, hd = bh & 7;
    const int s0 = (idx >> 3) << 8;              // q-tile start (256 rows)

    unsigned short* qptr = qkv + ((size_t)(b * SEQ + s0)) * QKVLD + hd * DKH;
    const unsigned short* kbase = qkv + ((size_t)(b * SEQ)) * QKVLD + 512 + hd * DKH;
    const unsigned short* vbase = qkv + ((size_t)(b * SEQ)) * QKVLD + 1024 + hd * DKH;

    // Q fragments (B-operand): lane -> Q[w*32+q32][dk = 16t + 8h .. +7]
    bf16x8 qf[4];
    {
        const unsigned short* qp = qptr + (size_t)(w * 32 + q32) * QKVLD + 8 * h;
        #pragma unroll
        for (int t = 0; t < 4; ++t)
            qf[t] = *(const bf16x8*)(qp + 16 * t);
    }

    // loop-invariant constants: zero C-operand, ones B-operand (bf16 1.0)
    f32x16 z16;
    #pragma unroll
    for (int i = 0; i < 16; ++i) z16[i] = 0.f;
    union { unsigned short us[8]; bf16x8 v; } onesu;
    #pragma unroll
    for (int j = 0; j < 8; ++j) onesu.us[j] = 0x3F80;
    const bf16x8 ones = onesu.v;

    // staging indices
    const int kr = tid >> 3, kc = (tid & 7) << 3;
    const int vr = tid & 63, vc = (tid >> 6) << 3;

    uint4 kreg, vreg;
    auto loadKV = [&](int t0) {
        kreg = *(const uint4*)(kbase + (size_t)(t0 + kr) * QKVLD + kc);
        vreg = *(const uint4*)(vbase + (size_t)(t0 + vr) * QKVLD + vc);
    };
    loadKV(0);

    f32x16 oacc0, oacc1, lacc;       // O[q rows][dk], row sums
    #pragma unroll
    for (int i = 0; i < 16; ++i) { oacc0[i] = 0.f; oacc1[i] = 0.f; lacc[i] = 0.f; }
    float m = -INFINITY;

    for (int t0 = 0; t0 < SEQ; t0 += 64) {
        const int cur = (t0 >> 6) & 1;
        *(uint4*)&Ks[cur][kr][kc] = kreg;
        {
            const unsigned short* vu = (const unsigned short*)&vreg;
            #pragma unroll
            for (int j = 0; j < 8; ++j) Vt[cur][vc + j][vr] = vu[j];
        }
        __syncthreads();

        if (t0 + 64 < SEQ) loadKV(t0 + 64);   // prefetch over compute

        // ---- QK^T swapped: D[kv][q]; first MFMA consumes the hoisted zero C
        f32x16 sa0, sa1;
        __builtin_amdgcn_s_setprio(1);
        {
            const bf16x8 k0 = *(const bf16x8*)&Ks[cur][q32     ][8 * h];
            const bf16x8 k1 = *(const bf16x8*)&Ks[cur][32 + q32][8 * h];
            sa0 = mfma32(k0, qf[0], z16);
            sa1 = mfma32(k1, qf[0], z16);
        }
        #pragma unroll
        for (int t = 1; t < 4; ++t) {
            const bf16x8 k0 = *(const bf16x8*)&Ks[cur][q32     ][16 * t + 8 * h];
            const bf16x8 k1 = *(const bf16x8*)&Ks[cur][32 + q32][16 * t + 8 * h];
            sa0 = mfma32(k0, qf[t], sa0);
            sa1 = mfma32(k1, qf[t], sa1);
        }
        __builtin_amdgcn_s_setprio(0);

        // ---- in-lane softmax (exp2 domain, defer-max) ----
        float pmax = fmaxf(sa0[0], sa1[0]);
        #pragma unroll
        for (int r = 1; r < 16; ++r)
            pmax = fmaxf(pmax, fmaxf(sa0[r], sa1[r]));
        if (__any(pmax > m + 8.f)) {          // rare after first tile
            // cross-half combine only when rescaling (pair shares q-row)
            unsigned xx = fbits(pmax), yy = xx;
            plswap(xx, yy);
            const float partner = (lane < 32) ? bitsf(yy) : bitsf(xx);
            pmax = fmaxf(pmax, partner);
            const float mnew = fmaxf(m, pmax);
            const float alpha = fexp2(m - mnew);   // first tile: 2^-inf = 0
            m = mnew;
            #pragma unroll
            for (int r = 0; r < 16; ++r) {
                const int qr = (r & 3) + 8 * (r >> 2) + 4 * h;
                const float ar = __shfl(alpha, qr, 64);
                oacc0[r] *= ar;
                oacc1[r] *= ar;
                lacc[r]  *= ar;
            }
        }
        // exp2 in place (bounded by 2^8 via defer-max)
        #pragma unroll
        for (int r = 0; r < 16; ++r) {
            sa0[r] = fexp2(sa0[r] - m);
            sa1[r] = fexp2(sa1[r] - m);
        }

        // ---- pack P to PV A-frags (cvt_pk + permlane32_swap) ----
        bf16x8 pa[4];
        #pragma unroll
        for (int blk = 0; blk < 2; ++blk) {
            const f32x16& p = blk ? sa1 : sa0;
            #pragma unroll
            for (int tt = 0; tt < 2; ++tt) {
                unsigned a0 = cvtpk(p[8 * tt + 0], p[8 * tt + 1]);
                unsigned a1 = cvtpk(p[8 * tt + 2], p[8 * tt + 3]);
                unsigned b0 = cvtpk(p[8 * tt + 4], p[8 * tt + 5]);
                unsigned b1 = cvtpk(p[8 * tt + 6], p[8 * tt + 7]);
                plswap(a0, b0);
                plswap(a1, b1);
                union { uint4 u; bf16x8 v; } cvt;
                cvt.u.x = a0; cvt.u.y = a1; cvt.u.z = b0; cvt.u.w = b1;
                pa[blk * 2 + tt] = cvt.v;
            }
        }

        // ---- O += P V ; row sums += P . 1  (MFMA-with-ones) ----
        __builtin_amdgcn_s_setprio(1);
        #pragma unroll
        for (int ttg = 0; ttg < 4; ++ttg) {    // kv 16-chunks
            const bf16x8 vf0 = *(const bf16x8*)&Vt[cur][q32     ][16 * ttg + 8 * h];
            const bf16x8 vf1 = *(const bf16x8*)&Vt[cur][32 + q32][16 * ttg + 8 * h];
            oacc0 = mfma32(pa[ttg], vf0, oacc0);
            oacc1 = mfma32(pa[ttg], vf1, oacc1);
            lacc  = mfma32(pa[ttg], ones, lacc);
        }
        __builtin_amdgcn_s_setprio(0);
    }

    // ---- final: normalize (lacc is reg-aligned with oacc), write O ----
    #pragma unroll
    for (int r = 0; r < 16; ++r) {
        const float invr = 1.f / lacc[r];
        const int qr = (r & 3) + 8 * (r >> 2) + 4 * h;
        unsigned short* op = qptr + (size_t)(w * 32 + qr) * QKVLD + q32;
        op[0]  = f2bf(oacc0[r] * invr);
        op[32] = f2bf(oacc1[r] * invr);
    }
}

// ---------------------------------------------------------------------------
// LayerNorm rows of 512; one wave per row. WF32: fp32 out; WB16: bf16 out.
// ---------------------------------------------------------------------------
template<bool WF32, bool WB16>
__global__ __launch_bounds__(256)
void ln_kernel(const float* __restrict__ in, const float* __restrict__ gg,
               const float* __restrict__ bb, float* __restrict__ outf,
               unsigned short* __restrict__ outb)
{
    const int row = blockIdx.x * 4 + (threadIdx.x >> 6);
    const int lane = threadIdx.x & 63;
    const float* p = in + (size_t)row * D_MODEL;

    const float4 a = *(const float4*)(p + lane * 4);
    const float4 c = *(const float4*)(p + 256 + lane * 4);
    float sum = a.x + a.y + a.z + a.w + c.x + c.y + c.z + c.w;
    float sq  = a.x*a.x + a.y*a.y + a.z*a.z + a.w*a.w
              + c.x*c.x + c.y*c.y + c.z*c.z + c.w*c.w;
    #pragma unroll
    for (int msk = 1; msk < 64; msk <<= 1) {
        sum += __shfl_xor(sum, msk, 64);
        sq  += __shfl_xor(sq,  msk, 64);
    }
    const float mean = sum * (1.f / 512.f);
    const float var  = sq * (1.f / 512.f) - mean * mean;
    const float rs   = rsqrtf(var + 1e-5f);

    const float4 g0 = *(const float4*)(gg + lane * 4);
    const float4 g1 = *(const float4*)(gg + 256 + lane * 4);
    const float4 b0 = *(const float4*)(bb + lane * 4);
    const float4 b1 = *(const float4*)(bb + 256 + lane * 4);

    float4 o0, o1;
    o0.x = (a.x - mean) * rs * g0.x + b0.x;
    o0.y = (a.y - mean) * rs * g0.y + b0.y;
    o0.z = (a.z - mean) * rs * g0.z + b0.z;
    o0.w = (a.w - mean) * rs * g0.w + b0.w;
    o1.x = (c.x - mean) * rs * g1.x + b1.x;
    o1.y = (c.y - mean) * rs * g1.y + b1.y;
    o1.z = (c.z - mean) * rs * g1.z + b1.z;
    o1.w = (c.w - mean) * rs * g1.w + b1.w;
    if constexpr (WF32) {
        *(float4*)(outf + (size_t)row * D_MODEL + lane * 4) = o0;
        *(float4*)(outf + (size_t)row * D_MODEL + 256 + lane * 4) = o1;
    }
    if constexpr (WB16) {
        uint2 pa, pb;
        pa.x = cvtpk(o0.x, o0.y);
        pa.y = cvtpk(o0.z, o0.w);
        pb.x = cvtpk(o1.x, o1.y);
        pb.y = cvtpk(o1.z, o1.w);
        *(uint2*)(outb + (size_t)row * D_MODEL + lane * 4) = pa;
        *(uint2*)(outb + (size_t)row * D_MODEL + 256 + lane * 4) = pb;
    }
}

// ---------------------------------------------------------------------------
// fp32 -> bf16 cast, 8 elems/thread
// ---------------------------------------------------------------------------
__global__ __launch_bounds__(256)
void cast_bf16(const float* __restrict__ in, unsigned short* __restrict__ out)
{
    const size_t i = ((size_t)blockIdx.x * 256 + threadIdx.x) * 8;
    const float4 a = *(const float4*)(in + i);
    const float4 b = *(const float4*)(in + i + 4);
    uint4 o;
    o.x = cvtpk(a.x, a.y);
    o.y = cvtpk(a.z, a.w);
    o.z = cvtpk(b.x, b.y);
    o.w = cvtpk(b.z, b.w);
    *(uint4*)(out + i) = o;
}

// ---------------------------------------------------------------------------
// Weight packing: per-head q/k/v weights -> rows 0..511 / 512..1023 /
// 1024..1535 of Wqkv[1536][512] bf16. q scaled by 0.125*log2e (exp2 softmax).
// ---------------------------------------------------------------------------
__global__ __launch_bounds__(256)
void pack_qkv(const float* __restrict__ wq, const float* __restrict__ wk,
              const float* __restrict__ wv, unsigned short* __restrict__ Wqkv)
{
    const int idx = blockIdx.x * 256 + threadIdx.x;   // n*512 + d, n in 0..511
    const int n = idx >> 9, d = idx & 511;
    const int h = n >> 6, c = n & 63;
    const size_t src = ((size_t)h * 512 + d) * 64 + c;
    Wqkv[idx]                 = f2bf(wq[src] * 0.18033688f);  // 0.125 * log2(e)
    Wqkv[idx + 512 * 512]     = f2bf(wk[src]);
    Wqkv[idx + 2 * 512 * 512] = f2bf(wv[src]);
}

// LDS-tiled transpose-cast: in fp32 [K][N] -> out bf16 [N][K], 32x32 tiles.
__global__ __launch_bounds__(256)
void pack_t(const float* __restrict__ in, unsigned short* __restrict__ out,
            int K, int N)
{
    __shared__ float t[32][33];
    const int kb = blockIdx.x << 5, nb = blockIdx.y << 5;
    const int c = threadIdx.x & 31, r0 = threadIdx.x >> 5;   // 8 row-groups
    #pragma unroll
    for (int j = 0; j < 32; j += 8)
        t[r0 + j][c] = in[(size_t)(kb + r0 + j) * N + nb + c];
    __syncthreads();
    #pragma unroll
    for (int j = 0; j < 32; j += 8)
        out[(size_t)(nb + r0 + j) * K + kb + c] = f2bf(t[c][r0 + j]);
}

// ---------------------------------------------------------------------------
extern "C" void kernel_launch(void* const* d_in, const int* in_sizes, int n_in,
                              void* d_out, int out_size, void* d_ws, size_t ws_size,
                              hipStream_t stream)
{
    (void)in_sizes; (void)n_in; (void)out_size;

    const float* x    = (const float*)d_in[0];
    const float* wq   = (const float*)d_in[1];
    const float* wk   = (const float*)d_in[2];
    const float* wv   = (const float*)d_in[3];
    const float* wo   = (const float*)d_in[4];
    const float* w1   = (const float*)d_in[5];
    const float* b1   = (const float*)d_in[6];
    const float* w2   = (const float*)d_in[7];
    const float* b2   = (const float*)d_in[8];
    const float* ln1g = (const float*)d_in[9];
    const float* ln1b = (const float*)d_in[10];
    const float* ln2g = (const float*)d_in[11];
    const float* ln2b = (const float*)d_in[12];
    float* out = (float*)d_out;

    // ---- workspace layout (bytes), fixed part ~90.2 MB ----
    const size_t QKV_BYTES = (size_t)MROWS * QKVLD * 2;      // 50.33 MB
    const size_t Y_BYTES   = (size_t)MROWS * D_MODEL * 4;    // 33.55 MB
    unsigned char* base = (unsigned char*)d_ws;
    unsigned short* qkv  = (unsigned short*)(base);
    float*          y    = (float*)(base + QKV_BYTES);
    unsigned short* Wqkv = (unsigned short*)(base + QKV_BYTES + Y_BYTES);
    unsigned short* wo_t = Wqkv + 3 * 512 * 512;
    unsigned short* w1_t = wo_t + 512 * 512;
    unsigned short* w2_t = w1_t + 2048 * 512;
    unsigned short* hid  = w2_t + 2048 * 512;

    const size_t hid_off = (size_t)((unsigned char*)hid - base);
    const size_t avail = (ws_size > hid_off) ? (ws_size - hid_off) : 0;
    int chunk = (int)(avail / ((size_t)DFF * 2));
    chunk &= ~127;
    if (chunk > MROWS) chunk = MROWS;
    if (chunk < 128)   chunk = 128;

    float* y2 = (float*)qkv;                       // qkv dead after WO GEMM
    unsigned short* xb  = (unsigned short*)d_out;  // bf16 x until LN1
    unsigned short* x1b = (unsigned short*)d_out;  // then bf16 x1

    // ---- weight packing + x cast ----
    pack_qkv<<<1024, 256, 0, stream>>>(wq, wk, wv, Wqkv);
    pack_t<<<dim3(16, 16), 256, 0, stream>>>(wo, wo_t, 512, 512);
    pack_t<<<dim3(16, 64), 256, 0, stream>>>(w1, w1_t, 512, 2048);
    pack_t<<<dim3(64, 16), 256, 0, stream>>>(w2, w2_t, 2048, 512);
    cast_bf16<<<(MROWS * D_MODEL) / (256 * 8), 256, 0, stream>>>(x, xb);

    const dim3 blk(256);

    // 1) fused q|k|v projection: xb[M][512] @ Wqkv^T -> qkv[M][1536]
    mfma_gemm<false, false, 0, false>
        <<<dim3(12, MROWS / 128), blk, 0, stream>>>(xb, Wqkv, nullptr, nullptr,
                                                    qkv, 512, 512, QKVLD);

    // 2) flash attention (O bf16 in place over q section), XCD-swizzled grid
    mfma_attn<<<dim3(512), dim3(512), 0, stream>>>(qkv);

    // 3) y = O @ wo + x   (fp32 out, fp32 residual)
    mfma_gemm<false, false, 1, true>
        <<<dim3(4, MROWS / 128), blk, 0, stream>>>(qkv, wo_t, nullptr, x, y,
                                                   512, QKVLD, 512);

    // 4) x1 = LN1(y): bf16 only into d_out (FFN2 residual reads bf16)
    ln_kernel<false, true><<<MROWS / 4, blk, 0, stream>>>(y, ln1g, ln1b,
                                                          nullptr, x1b);

    // 5+6) FFN, chunked over rows (chunk multiple of 128)
    for (int r0 = 0; r0 < MROWS; r0 += chunk) {
        const int rows = (r0 + chunk <= MROWS) ? chunk : (MROWS - r0);
        mfma_gemm<true, true, 0, false>
            <<<dim3(DFF / 128, rows / 128), blk, 0, stream>>>(
                x1b + (size_t)r0 * D_MODEL, w1_t, b1, nullptr, hid,
                512, 512, DFF);
        mfma_gemm<true, false, 2, true>
            <<<dim3(4, rows / 128), blk, 0, stream>>>(
                hid, w2_t, b2, x1b + (size_t)r0 * D_MODEL,
                y2 + (size_t)r0 * D_MODEL, DFF, DFF, 512);
    }

    // 7) out = LN2(y2)
    ln_kernel<true, false><<<MROWS / 4, blk, 0, stream>>>(y2, ln2g, ln2b,
                                                          out, nullptr);
}

// Round 15
// 292.641 us; speedup vs baseline: 1.0410x; 1.0410x over previous
//
#include <hip/hip_runtime.h>
#include <hip/hip_bf16.h>
#include <math.h>

// ---------------------------------------------------------------------------
// EncoderLayer, bf16-MFMA mixed precision for MI355X (gfx950).
// B=8, S=2048, D=512, H=8, DK=64, DFF=2048, M=16384.
// Round-15: A/B decomposition of r14's attn trims. r14 regressed (94.5 ->
// 111.8us) with BOTH pipes under-used -> dependency stalls from the
// lacc MFMA-with-ones (trim 2: +25% MFMA as a serial chain, minus the
// independent VALU adds that hid latency). REVERT trim 2 (restore r13's
// per-lane lsum + final permlane combine); KEEP trim 1 (hoisted zero-C)
// and trim 3 (pmax cross-half combine inside the rare rescale branch).
// GEMM/LN/pack byte-identical to r13/r14.
// ---------------------------------------------------------------------------

#define D_MODEL 512
#define NHEAD   8
#define DKH     64
#define SEQ     2048
#define BATCH   8
#define DFF     2048
#define MROWS   (BATCH * SEQ)          // 16384
#define QKVLD   1536                   // fused q|k|v row stride

typedef __bf16 bf16x8 __attribute__((ext_vector_type(8)));
typedef float  f32x4  __attribute__((ext_vector_type(4)));
typedef float  f32x16 __attribute__((ext_vector_type(16)));

__device__ __forceinline__ unsigned short f2bf(float f) {
    union { float f; unsigned u; } v; v.f = f;
    return (unsigned short)((v.u + 0x7FFFu + ((v.u >> 16) & 1u)) >> 16);
}

__device__ __forceinline__ float bf2f(unsigned short u) {
    union { unsigned u; float f; } v; v.u = (unsigned)u << 16;
    return v.f;
}

__device__ __forceinline__ unsigned cvtpk(float a, float b) {   // bf16(a)|bf16(b)<<16
    unsigned r;
    asm("v_cvt_pk_bf16_f32 %0, %1, %2" : "=v"(r) : "v"(a), "v"(b));
    return r;
}

__device__ __forceinline__ float fexp2(float x) {   // raw v_exp_f32 (2^x)
    float r; asm("v_exp_f32 %0, %1" : "=v"(r) : "v"(x)); return r;
}

// v_permlane32_swap_b32: x<-[x(0:31)|y(0:31)], y<-[x(32:63)|y(32:63)]
__device__ __forceinline__ void plswap(unsigned& x, unsigned& y) {
    asm volatile("v_permlane32_swap_b32 %0, %1" : "+v"(x), "+v"(y));
}

__device__ __forceinline__ unsigned fbits(float f) {
    union { float f; unsigned u; } v; v.f = f; return v.u;
}
__device__ __forceinline__ float bitsf(unsigned u) {
    union { unsigned u; float f; } v; v.u = u; return v.f;
}

__device__ __forceinline__ f32x4 mfma16(bf16x8 a, bf16x8 b, f32x4 c) {
    return __builtin_amdgcn_mfma_f32_16x16x32_bf16(a, b, c, 0, 0, 0);
}
__device__ __forceinline__ f32x16 mfma32(bf16x8 a, bf16x8 b, f32x16 c) {
    return __builtin_amdgcn_mfma_f32_32x32x16_bf16(a, b, c, 0, 0, 0);
}

// async global -> LDS, 16 B per lane; lds base must be wave-uniform
__device__ __forceinline__ void gld_lds16(const unsigned short* g, unsigned short* l) {
    __builtin_amdgcn_global_load_lds(
        (const __attribute__((address_space(1))) unsigned int*)g,
        (__attribute__((address_space(3))) unsigned int*)l, 16, 0, 0);
}

// ---------------------------------------------------------------------------
// bf16 MFMA GEMM (unchanged): 128x128 tile, BK=32, 4 waves, double-buffered
// global_load_lds staging. RESMODE: 0 none, 1 fp32, 2 bf16.
// ---------------------------------------------------------------------------
template<bool BIAS, bool RELU, int RESMODE, bool OUTF32>
__global__ __launch_bounds__(256)
void mfma_gemm(const unsigned short* __restrict__ Av,
               const unsigned short* __restrict__ Bt,
               const float* __restrict__ bias, const void* __restrict__ resv,
               void* __restrict__ Cv, int Kdim, int lda, int ldc)
{
    __shared__ unsigned short As[2][128][32];
    __shared__ unsigned short Bs[2][128][32];

    const int tid  = threadIdx.x;
    const int lane = tid & 63;
    const int w    = tid >> 6;
    const int mq   = (w >> 1) << 6;
    const int nq   = (w & 1) << 6;
    const int lrow = lane & 15;
    const int g    = lane >> 4;
    const int lk   = g << 3;

    const int row0 = blockIdx.y << 7;
    const int col0 = blockIdx.x << 7;

    const int c0   = w << 5;
    const int srow = lane >> 2;
    const int scol = (lane & 3) << 3;
    const size_t aoff = (size_t)(row0 + c0 + srow) * lda  + scol;
    const size_t boff = (size_t)(col0 + c0 + srow) * Kdim + scol;

    auto stage = [&](int buf, int kt) {
        gld_lds16(Av + aoff + kt,                        &As[buf][c0     ][0]);
        gld_lds16(Av + aoff + (size_t)16 * lda  + kt,    &As[buf][c0 + 16][0]);
        gld_lds16(Bt + boff + kt,                        &Bs[buf][c0     ][0]);
        gld_lds16(Bt + boff + (size_t)16 * Kdim + kt,    &Bs[buf][c0 + 16][0]);
    };

    const f32x4 zero = {0.f, 0.f, 0.f, 0.f};
    f32x4 acc[4][4];
    #pragma unroll
    for (int i = 0; i < 4; ++i)
        #pragma unroll
        for (int j = 0; j < 4; ++j) acc[i][j] = zero;

    stage(0, 0);
    __syncthreads();

    int cur = 0;
    for (int kt = 0; kt < Kdim; kt += 32) {
        if (kt + 32 < Kdim) stage(cur ^ 1, kt + 32);

        bf16x8 af[4], bfv[4];
        #pragma unroll
        for (int mf = 0; mf < 4; ++mf)
            af[mf] = *(const bf16x8*)&As[cur][mq + mf * 16 + lrow][lk];
        #pragma unroll
        for (int nf = 0; nf < 4; ++nf)
            bfv[nf] = *(const bf16x8*)&Bs[cur][nq + nf * 16 + lrow][lk];
        #pragma unroll
        for (int mf = 0; mf < 4; ++mf)
            #pragma unroll
            for (int nf = 0; nf < 4; ++nf)
                acc[mf][nf] = mfma16(af[mf], bfv[nf], acc[mf][nf]);

        __syncthreads();
        cur ^= 1;
    }

    const int orow = row0 + mq + g * 4;
    const int ocol = col0 + nq + lrow;
    #pragma unroll
    for (int mf = 0; mf < 4; ++mf) {
        #pragma unroll
        for (int nf = 0; nf < 4; ++nf) {
            const int cc = ocol + nf * 16;
            float bv = 0.f;
            if constexpr (BIAS) bv = bias[cc];
            float v[4];
            #pragma unroll
            for (int r = 0; r < 4; ++r) {
                const int rr = orow + mf * 16 + r;
                v[r] = acc[mf][nf][r];
                if constexpr (BIAS) v[r] += bv;
                if constexpr (RELU) v[r] = fmaxf(v[r], 0.f);
                if constexpr (RESMODE == 1)
                    v[r] += ((const float*)resv)[(size_t)rr * ldc + cc];
                if constexpr (RESMODE == 2)
                    v[r] += bf2f(((const unsigned short*)resv)[(size_t)rr * ldc + cc]);
                if constexpr (OUTF32) ((float*)Cv)[(size_t)rr * ldc + cc] = v[r];
            }
            if constexpr (!OUTF32) {
                const unsigned u01 = cvtpk(v[0], v[1]);
                const unsigned u23 = cvtpk(v[2], v[3]);
                unsigned short* cp = (unsigned short*)Cv + (size_t)(orow + mf * 16) * ldc + cc;
                cp[0]                 = (unsigned short)u01;
                cp[(size_t)ldc]       = (unsigned short)(u01 >> 16);
                cp[(size_t)ldc * 2]   = (unsigned short)u23;
                cp[(size_t)ldc * 3]   = (unsigned short)(u23 >> 16);
            }
        }
    }
}

// ---------------------------------------------------------------------------
// Flash attention v8 (r13 structure + trims 1/3 only):
// swapped QK^T, 32x32x16 MFMA, in-register P. 8 waves x 32 q-rows,
// 512 blocks, KV tiles of 64 double-buffered (single barrier/tile).
// Lane owns q = lane&31; h = lane>>5 is the kv half.
// Trim 1: QK accumulators consume a loop-invariant zero C (no per-tile movs).
// Trim 3: cross-half pmax combine only inside the rare rescale branch.
// Row sums: per-lane float adds (r13) + final permlane combine (NO lacc MFMA).
// ---------------------------------------------------------------------------
__global__ __launch_bounds__(512, 4)
void mfma_attn(unsigned short* __restrict__ qkv)
{
    __shared__ unsigned short Ks[2][64][72];   // K tile [buf][kv][dk]
    __shared__ unsigned short Vt[2][64][72];   // V transposed [buf][dk][kv]

    const int tid  = threadIdx.x;
    const int lane = tid & 63;
    const int w    = tid >> 6;
    const int q32  = lane & 31;      // this lane's q (and kv-row selector)
    const int h    = lane >> 5;      // kv half / k-chunk selector

    // XCD swizzle: 512 blocks = 8 xcd x (8 bh-groups x 8 q-tiles)
    const int bid  = blockIdx.x;
    const int idx  = bid >> 3;
    const int bh   = (bid & 7) * 8 + (idx & 7);
    const int b  = bh >> 3, hd = bh & 7;
    const int s0 = (idx >> 3) << 8;              // q-tile start (256 rows)

    unsigned short* qptr = qkv + ((size_t)(b * SEQ + s0)) * QKVLD + hd * DKH;
    const unsigned short* kbase = qkv + ((size_t)(b * SEQ)) * QKVLD + 512 + hd * DKH;
    const unsigned short* vbase = qkv + ((size_t)(b * SEQ)) * QKVLD + 1024 + hd * DKH;

    // Q fragments (B-operand): lane -> Q[w*32+q32][dk = 16t + 8h .. +7]
    bf16x8 qf[4];
    {
        const unsigned short* qp = qptr + (size_t)(w * 32 + q32) * QKVLD + 8 * h;
        #pragma unroll
        for (int t = 0; t < 4; ++t)
            qf[t] = *(const bf16x8*)(qp + 16 * t);
    }

    // loop-invariant zero C-operand (trim 1)
    f32x16 z16;
    #pragma unroll
    for (int i = 0; i < 16; ++i) z16[i] = 0.f;

    // staging indices
    const int kr = tid >> 3, kc = (tid & 7) << 3;
    const int vr = tid & 63, vc = (tid >> 6) << 3;

    uint4 kreg, vreg;
    auto loadKV = [&](int t0) {
        kreg = *(const uint4*)(kbase + (size_t)(t0 + kr) * QKVLD + kc);
        vreg = *(const uint4*)(vbase + (size_t)(t0 + vr) * QKVLD + vc);
    };
    loadKV(0);

    f32x16 oacc0, oacc1;             // O[q rows][dk = dt*32 + q32]
    #pragma unroll
    for (int i = 0; i < 16; ++i) { oacc0[i] = 0.f; oacc1[i] = 0.f; }
    float m = -INFINITY, lsum = 0.f;

    for (int t0 = 0; t0 < SEQ; t0 += 64) {
        const int cur = (t0 >> 6) & 1;
        *(uint4*)&Ks[cur][kr][kc] = kreg;
        {
            const unsigned short* vu = (const unsigned short*)&vreg;
            #pragma unroll
            for (int j = 0; j < 8; ++j) Vt[cur][vc + j][vr] = vu[j];
        }
        __syncthreads();

        if (t0 + 64 < SEQ) loadKV(t0 + 64);   // prefetch over compute

        // ---- QK^T swapped: D[kv][q]; first MFMA consumes hoisted zero C ----
        f32x16 sa0, sa1;
        __builtin_amdgcn_s_setprio(1);
        {
            const bf16x8 k0 = *(const bf16x8*)&Ks[cur][q32     ][8 * h];
            const bf16x8 k1 = *(const bf16x8*)&Ks[cur][32 + q32][8 * h];
            sa0 = mfma32(k0, qf[0], z16);
            sa1 = mfma32(k1, qf[0], z16);
        }
        #pragma unroll
        for (int t = 1; t < 4; ++t) {
            const bf16x8 k0 = *(const bf16x8*)&Ks[cur][q32     ][16 * t + 8 * h];
            const bf16x8 k1 = *(const bf16x8*)&Ks[cur][32 + q32][16 * t + 8 * h];
            sa0 = mfma32(k0, qf[t], sa0);
            sa1 = mfma32(k1, qf[t], sa1);
        }
        __builtin_amdgcn_s_setprio(0);

        // ---- in-lane softmax (exp2 domain, defer-max) ----
        float pmax = fmaxf(sa0[0], sa1[0]);
        #pragma unroll
        for (int r = 1; r < 16; ++r)
            pmax = fmaxf(pmax, fmaxf(sa0[r], sa1[r]));
        if (__any(pmax > m + 8.f)) {          // rare after first tile
            // cross-half combine only when rescaling (trim 3)
            unsigned xx = fbits(pmax), yy = xx;
            plswap(xx, yy);
            const float partner = (lane < 32) ? bitsf(yy) : bitsf(xx);
            pmax = fmaxf(pmax, partner);
            const float mnew = fmaxf(m, pmax);
            const float alpha = fexp2(m - mnew);   // first tile: 2^-inf = 0
            m = mnew;
            lsum *= alpha;
            #pragma unroll
            for (int r = 0; r < 16; ++r) {
                const int qr = (r & 3) + 8 * (r >> 2) + 4 * h;
                const float ar = __shfl(alpha, qr, 64);
                oacc0[r] *= ar;
                oacc1[r] *= ar;
            }
        }
        // exp2 in place + lazy per-lane sum (r13)
        #pragma unroll
        for (int r = 0; r < 16; ++r) {
            sa0[r] = fexp2(sa0[r] - m);
            sa1[r] = fexp2(sa1[r] - m);
            lsum += sa0[r] + sa1[r];
        }

        // ---- pack P to PV A-frags (cvt_pk + permlane32_swap) ----
        bf16x8 pa[4];
        #pragma unroll
        for (int blk = 0; blk < 2; ++blk) {
            const f32x16& p = blk ? sa1 : sa0;
            #pragma unroll
            for (int tt = 0; tt < 2; ++tt) {
                unsigned a0 = cvtpk(p[8 * tt + 0], p[8 * tt + 1]);
                unsigned a1 = cvtpk(p[8 * tt + 2], p[8 * tt + 3]);
                unsigned b0 = cvtpk(p[8 * tt + 4], p[8 * tt + 5]);
                unsigned b1 = cvtpk(p[8 * tt + 6], p[8 * tt + 7]);
                plswap(a0, b0);
                plswap(a1, b1);
                union { uint4 u; bf16x8 v; } cvt;
                cvt.u.x = a0; cvt.u.y = a1; cvt.u.z = b0; cvt.u.w = b1;
                pa[blk * 2 + tt] = cvt.v;
            }
        }

        // ---- O += P V  (B = V from plain-transposed LDS) ----
        __builtin_amdgcn_s_setprio(1);
        #pragma unroll
        for (int ttg = 0; ttg < 4; ++ttg) {    // kv 16-chunks
            const bf16x8 vf0 = *(const bf16x8*)&Vt[cur][q32     ][16 * ttg + 8 * h];
            const bf16x8 vf1 = *(const bf16x8*)&Vt[cur][32 + q32][16 * ttg + 8 * h];
            oacc0 = mfma32(pa[ttg], vf0, oacc0);
            oacc1 = mfma32(pa[ttg], vf1, oacc1);
        }
        __builtin_amdgcn_s_setprio(0);
    }

    // ---- final: pair-combine row sums, normalize, write O in place ----
    float ltot;
    {
        unsigned x = fbits(lsum), y = x;
        plswap(x, y);
        const float partner = (lane < 32) ? bitsf(y) : bitsf(x);
        ltot = lsum + partner;                // symmetric: full row sum for q
    }
    const float inv = 1.f / ltot;
    #pragma unroll
    for (int r = 0; r < 16; ++r) {
        const int qr = (r & 3) + 8 * (r >> 2) + 4 * h;
        const float invr = __shfl(inv, qr, 64);
        unsigned short* op = qptr + (size_t)(w * 32 + qr) * QKVLD + q32;
        op[0]  = f2bf(oacc0[r] * invr);
        op[32] = f2bf(oacc1[r] * invr);
    }
}

// ---------------------------------------------------------------------------
// LayerNorm rows of 512; one wave per row. WF32: fp32 out; WB16: bf16 out.
// ---------------------------------------------------------------------------
template<bool WF32, bool WB16>
__global__ __launch_bounds__(256)
void ln_kernel(const float* __restrict__ in, const float* __restrict__ gg,
               const float* __restrict__ bb, float* __restrict__ outf,
               unsigned short* __restrict__ outb)
{
    const int row = blockIdx.x * 4 + (threadIdx.x >> 6);
    const int lane = threadIdx.x & 63;
    const float* p = in + (size_t)row * D_MODEL;

    const float4 a = *(const float4*)(p + lane * 4);
    const float4 c = *(const float4*)(p + 256 + lane * 4);
    float sum = a.x + a.y + a.z + a.w + c.x + c.y + c.z + c.w;
    float sq  = a.x*a.x + a.y*a.y + a.z*a.z + a.w*a.w
              + c.x*c.x + c.y*c.y + c.z*c.z + c.w*c.w;
    #pragma unroll
    for (int msk = 1; msk < 64; msk <<= 1) {
        sum += __shfl_xor(sum, msk, 64);
        sq  += __shfl_xor(sq,  msk, 64);
    }
    const float mean = sum * (1.f / 512.f);
    const float var  = sq * (1.f / 512.f) - mean * mean;
    const float rs   = rsqrtf(var + 1e-5f);

    const float4 g0 = *(const float4*)(gg + lane * 4);
    const float4 g1 = *(const float4*)(gg + 256 + lane * 4);
    const float4 b0 = *(const float4*)(bb + lane * 4);
    const float4 b1 = *(const float4*)(bb + 256 + lane * 4);

    float4 o0, o1;
    o0.x = (a.x - mean) * rs * g0.x + b0.x;
    o0.y = (a.y - mean) * rs * g0.y + b0.y;
    o0.z = (a.z - mean) * rs * g0.z + b0.z;
    o0.w = (a.w - mean) * rs * g0.w + b0.w;
    o1.x = (c.x - mean) * rs * g1.x + b1.x;
    o1.y = (c.y - mean) * rs * g1.y + b1.y;
    o1.z = (c.z - mean) * rs * g1.z + b1.z;
    o1.w = (c.w - mean) * rs * g1.w + b1.w;
    if constexpr (WF32) {
        *(float4*)(outf + (size_t)row * D_MODEL + lane * 4) = o0;
        *(float4*)(outf + (size_t)row * D_MODEL + 256 + lane * 4) = o1;
    }
    if constexpr (WB16) {
        uint2 pa, pb;
        pa.x = cvtpk(o0.x, o0.y);
        pa.y = cvtpk(o0.z, o0.w);
        pb.x = cvtpk(o1.x, o1.y);
        pb.y = cvtpk(o1.z, o1.w);
        *(uint2*)(outb + (size_t)row * D_MODEL + lane * 4) = pa;
        *(uint2*)(outb + (size_t)row * D_MODEL + 256 + lane * 4) = pb;
    }
}

// ---------------------------------------------------------------------------
// fp32 -> bf16 cast, 8 elems/thread
// ---------------------------------------------------------------------------
__global__ __launch_bounds__(256)
void cast_bf16(const float* __restrict__ in, unsigned short* __restrict__ out)
{
    const size_t i = ((size_t)blockIdx.x * 256 + threadIdx.x) * 8;
    const float4 a = *(const float4*)(in + i);
    const float4 b = *(const float4*)(in + i + 4);
    uint4 o;
    o.x = cvtpk(a.x, a.y);
    o.y = cvtpk(a.z, a.w);
    o.z = cvtpk(b.x, b.y);
    o.w = cvtpk(b.z, b.w);
    *(uint4*)(out + i) = o;
}

// ---------------------------------------------------------------------------
// Weight packing: per-head q/k/v weights -> rows 0..511 / 512..1023 /
// 1024..1535 of Wqkv[1536][512] bf16. q scaled by 0.125*log2e (exp2 softmax).
// ---------------------------------------------------------------------------
__global__ __launch_bounds__(256)
void pack_qkv(const float* __restrict__ wq, const float* __restrict__ wk,
              const float* __restrict__ wv, unsigned short* __restrict__ Wqkv)
{
    const int idx = blockIdx.x * 256 + threadIdx.x;   // n*512 + d, n in 0..511
    const int n = idx >> 9, d = idx & 511;
    const int h = n >> 6, c = n & 63;
    const size_t src = ((size_t)h * 512 + d) * 64 + c;
    Wqkv[idx]                 = f2bf(wq[src] * 0.18033688f);  // 0.125 * log2(e)
    Wqkv[idx + 512 * 512]     = f2bf(wk[src]);
    Wqkv[idx + 2 * 512 * 512] = f2bf(wv[src]);
}

// LDS-tiled transpose-cast: in fp32 [K][N] -> out bf16 [N][K], 32x32 tiles.
__global__ __launch_bounds__(256)
void pack_t(const float* __restrict__ in, unsigned short* __restrict__ out,
            int K, int N)
{
    __shared__ float t[32][33];
    const int kb = blockIdx.x << 5, nb = blockIdx.y << 5;
    const int c = threadIdx.x & 31, r0 = threadIdx.x >> 5;   // 8 row-groups
    #pragma unroll
    for (int j = 0; j < 32; j += 8)
        t[r0 + j][c] = in[(size_t)(kb + r0 + j) * N + nb + c];
    __syncthreads();
    #pragma unroll
    for (int j = 0; j < 32; j += 8)
        out[(size_t)(nb + r0 + j) * K + kb + c] = f2bf(t[c][r0 + j]);
}

// ---------------------------------------------------------------------------
extern "C" void kernel_launch(void* const* d_in, const int* in_sizes, int n_in,
                              void* d_out, int out_size, void* d_ws, size_t ws_size,
                              hipStream_t stream)
{
    (void)in_sizes; (void)n_in; (void)out_size;

    const float* x    = (const float*)d_in[0];
    const float* wq   = (const float*)d_in[1];
    const float* wk   = (const float*)d_in[2];
    const float* wv   = (const float*)d_in[3];
    const float* wo   = (const float*)d_in[4];
    const float* w1   = (const float*)d_in[5];
    const float* b1   = (const float*)d_in[6];
    const float* w2   = (const float*)d_in[7];
    const float* b2   = (const float*)d_in[8];
    const float* ln1g = (const float*)d_in[9];
    const float* ln1b = (const float*)d_in[10];
    const float* ln2g = (const float*)d_in[11];
    const float* ln2b = (const float*)d_in[12];
    float* out = (float*)d_out;

    // ---- workspace layout (bytes), fixed part ~90.2 MB ----
    const size_t QKV_BYTES = (size_t)MROWS * QKVLD * 2;      // 50.33 MB
    const size_t Y_BYTES   = (size_t)MROWS * D_MODEL * 4;    // 33.55 MB
    unsigned char* base = (unsigned char*)d_ws;
    unsigned short* qkv  = (unsigned short*)(base);
    float*          y    = (float*)(base + QKV_BYTES);
    unsigned short* Wqkv = (unsigned short*)(base + QKV_BYTES + Y_BYTES);
    unsigned short* wo_t = Wqkv + 3 * 512 * 512;
    unsigned short* w1_t = wo_t + 512 * 512;
    unsigned short* w2_t = w1_t + 2048 * 512;
    unsigned short* hid  = w2_t + 2048 * 512;

    const size_t hid_off = (size_t)((unsigned char*)hid - base);
    const size_t avail = (ws_size > hid_off) ? (ws_size - hid_off) : 0;
    int chunk = (int)(avail / ((size_t)DFF * 2));
    chunk &= ~127;
    if (chunk > MROWS) chunk = MROWS;
    if (chunk < 128)   chunk = 128;

    float* y2 = (float*)qkv;                       // qkv dead after WO GEMM
    unsigned short* xb  = (unsigned short*)d_out;  // bf16 x until LN1
    unsigned short* x1b = (unsigned short*)d_out;  // then bf16 x1

    // ---- weight packing + x cast ----
    pack_qkv<<<1024, 256, 0, stream>>>(wq, wk, wv, Wqkv);
    pack_t<<<dim3(16, 16), 256, 0, stream>>>(wo, wo_t, 512, 512);
    pack_t<<<dim3(16, 64), 256, 0, stream>>>(w1, w1_t, 512, 2048);
    pack_t<<<dim3(64, 16), 256, 0, stream>>>(w2, w2_t, 2048, 512);
    cast_bf16<<<(MROWS * D_MODEL) / (256 * 8), 256, 0, stream>>>(x, xb);

    const dim3 blk(256);

    // 1) fused q|k|v projection: xb[M][512] @ Wqkv^T -> qkv[M][1536]
    mfma_gemm<false, false, 0, false>
        <<<dim3(12, MROWS / 128), blk, 0, stream>>>(xb, Wqkv, nullptr, nullptr,
                                                    qkv, 512, 512, QKVLD);

    // 2) flash attention (O bf16 in place over q section), XCD-swizzled grid
    mfma_attn<<<dim3(512), dim3(512), 0, stream>>>(qkv);

    // 3) y = O @ wo + x   (fp32 out, fp32 residual)
    mfma_gemm<false, false, 1, true>
        <<<dim3(4, MROWS / 128), blk, 0, stream>>>(qkv, wo_t, nullptr, x, y,
                                                   512, QKVLD, 512);

    // 4) x1 = LN1(y): bf16 only into d_out (FFN2 residual reads bf16)
    ln_kernel<false, true><<<MROWS / 4, blk, 0, stream>>>(y, ln1g, ln1b,
                                                          nullptr, x1b);

    // 5+6) FFN, chunked over rows (chunk multiple of 128)
    for (int r0 = 0; r0 < MROWS; r0 += chunk) {
        const int rows = (r0 + chunk <= MROWS) ? chunk : (MROWS - r0);
        mfma_gemm<true, true, 0, false>
            <<<dim3(DFF / 128, rows / 128), blk, 0, stream>>>(
                x1b + (size_t)r0 * D_MODEL, w1_t, b1, nullptr, hid,
                512, 512, DFF);
        mfma_gemm<true, false, 2, true>
            <<<dim3(4, rows / 128), blk, 0, stream>>>(
                hid, w2_t, b2, x1b + (size_t)r0 * D_MODEL,
                y2 + (size_t)r0 * D_MODEL, DFF, DFF, 512);
    }

    // 7) out = LN2(y2)
    ln_kernel<true, false><<<MROWS / 4, blk, 0, stream>>>(y2, ln2g, ln2b,
                                                          out, nullptr);
}

// Round 17
// 292.445 us; speedup vs baseline: 1.0417x; 1.0007x over previous
//
#include <hip/hip_runtime.h>
#include <hip/hip_bf16.h>
#include <math.h>

// ---------------------------------------------------------------------------
// EncoderLayer, bf16-MFMA mixed precision for MI355X (gfx950).
// B=8, S=2048, D=512, H=8, DK=64, DFF=2048, M=16384.
// Round-17: REVERT to the round-15 kernel (last fully-validated, 292.6us).
// r16's 256x128 GEMM passed first validation but diverged after graph
// replays (absmax 4.37) -- an intra-kernel race in the 8-wave single-barrier
// staging that can't be race-screened in this harness; abandoned.
// State: attn at VALU floor (swapped-QK 32x32, in-register P, defer-max,
// conflicts=0); GEMMs at the 2-phase structural ceiling; LN/pack at HBM floor.
// ---------------------------------------------------------------------------

#define D_MODEL 512
#define NHEAD   8
#define DKH     64
#define SEQ     2048
#define BATCH   8
#define DFF     2048
#define MROWS   (BATCH * SEQ)          // 16384
#define QKVLD   1536                   // fused q|k|v row stride

typedef __bf16 bf16x8 __attribute__((ext_vector_type(8)));
typedef float  f32x4  __attribute__((ext_vector_type(4)));
typedef float  f32x16 __attribute__((ext_vector_type(16)));

__device__ __forceinline__ unsigned short f2bf(float f) {
    union { float f; unsigned u; } v; v.f = f;
    return (unsigned short)((v.u + 0x7FFFu + ((v.u >> 16) & 1u)) >> 16);
}

__device__ __forceinline__ float bf2f(unsigned short u) {
    union { unsigned u; float f; } v; v.u = (unsigned)u << 16;
    return v.f;
}

__device__ __forceinline__ unsigned cvtpk(float a, float b) {   // bf16(a)|bf16(b)<<16
    unsigned r;
    asm("v_cvt_pk_bf16_f32 %0, %1, %2" : "=v"(r) : "v"(a), "v"(b));
    return r;
}

__device__ __forceinline__ float fexp2(float x) {   // raw v_exp_f32 (2^x)
    float r; asm("v_exp_f32 %0, %1" : "=v"(r) : "v"(x)); return r;
}

// v_permlane32_swap_b32: x<-[x(0:31)|y(0:31)], y<-[x(32:63)|y(32:63)]
__device__ __forceinline__ void plswap(unsigned& x, unsigned& y) {
    asm volatile("v_permlane32_swap_b32 %0, %1" : "+v"(x), "+v"(y));
}

__device__ __forceinline__ unsigned fbits(float f) {
    union { float f; unsigned u; } v; v.f = f; return v.u;
}
__device__ __forceinline__ float bitsf(unsigned u) {
    union { unsigned u; float f; } v; v.u = u; return v.f;
}

__device__ __forceinline__ f32x4 mfma16(bf16x8 a, bf16x8 b, f32x4 c) {
    return __builtin_amdgcn_mfma_f32_16x16x32_bf16(a, b, c, 0, 0, 0);
}
__device__ __forceinline__ f32x16 mfma32(bf16x8 a, bf16x8 b, f32x16 c) {
    return __builtin_amdgcn_mfma_f32_32x32x16_bf16(a, b, c, 0, 0, 0);
}

// async global -> LDS, 16 B per lane; lds base must be wave-uniform
__device__ __forceinline__ void gld_lds16(const unsigned short* g, unsigned short* l) {
    __builtin_amdgcn_global_load_lds(
        (const __attribute__((address_space(1))) unsigned int*)g,
        (__attribute__((address_space(3))) unsigned int*)l, 16, 0, 0);
}

// ---------------------------------------------------------------------------
// bf16 MFMA GEMM (proven 128x128 template): BK=32, 256 threads = 4 waves,
// each wave a 64x64 quadrant (4x4 fragments of 16x16x32). Double-buffered
// global_load_lds staging (issue next tile before MFMAs of current; one
// barrier per K-step). RESMODE: 0 none, 1 fp32, 2 bf16.
// ---------------------------------------------------------------------------
template<bool BIAS, bool RELU, int RESMODE, bool OUTF32>
__global__ __launch_bounds__(256)
void mfma_gemm(const unsigned short* __restrict__ Av,
               const unsigned short* __restrict__ Bt,
               const float* __restrict__ bias, const void* __restrict__ resv,
               void* __restrict__ Cv, int Kdim, int lda, int ldc)
{
    __shared__ unsigned short As[2][128][32];
    __shared__ unsigned short Bs[2][128][32];

    const int tid  = threadIdx.x;
    const int lane = tid & 63;
    const int w    = tid >> 6;
    const int mq   = (w >> 1) << 6;
    const int nq   = (w & 1) << 6;
    const int lrow = lane & 15;
    const int g    = lane >> 4;
    const int lk   = g << 3;

    const int row0 = blockIdx.y << 7;
    const int col0 = blockIdx.x << 7;

    const int c0   = w << 5;
    const int srow = lane >> 2;
    const int scol = (lane & 3) << 3;
    const size_t aoff = (size_t)(row0 + c0 + srow) * lda  + scol;
    const size_t boff = (size_t)(col0 + c0 + srow) * Kdim + scol;

    auto stage = [&](int buf, int kt) {
        gld_lds16(Av + aoff + kt,                        &As[buf][c0     ][0]);
        gld_lds16(Av + aoff + (size_t)16 * lda  + kt,    &As[buf][c0 + 16][0]);
        gld_lds16(Bt + boff + kt,                        &Bs[buf][c0     ][0]);
        gld_lds16(Bt + boff + (size_t)16 * Kdim + kt,    &Bs[buf][c0 + 16][0]);
    };

    const f32x4 zero = {0.f, 0.f, 0.f, 0.f};
    f32x4 acc[4][4];
    #pragma unroll
    for (int i = 0; i < 4; ++i)
        #pragma unroll
        for (int j = 0; j < 4; ++j) acc[i][j] = zero;

    stage(0, 0);
    __syncthreads();

    int cur = 0;
    for (int kt = 0; kt < Kdim; kt += 32) {
        if (kt + 32 < Kdim) stage(cur ^ 1, kt + 32);

        bf16x8 af[4], bfv[4];
        #pragma unroll
        for (int mf = 0; mf < 4; ++mf)
            af[mf] = *(const bf16x8*)&As[cur][mq + mf * 16 + lrow][lk];
        #pragma unroll
        for (int nf = 0; nf < 4; ++nf)
            bfv[nf] = *(const bf16x8*)&Bs[cur][nq + nf * 16 + lrow][lk];
        #pragma unroll
        for (int mf = 0; mf < 4; ++mf)
            #pragma unroll
            for (int nf = 0; nf < 4; ++nf)
                acc[mf][nf] = mfma16(af[mf], bfv[nf], acc[mf][nf]);

        __syncthreads();
        cur ^= 1;
    }

    const int orow = row0 + mq + g * 4;
    const int ocol = col0 + nq + lrow;
    #pragma unroll
    for (int mf = 0; mf < 4; ++mf) {
        #pragma unroll
        for (int nf = 0; nf < 4; ++nf) {
            const int cc = ocol + nf * 16;
            float bv = 0.f;
            if constexpr (BIAS) bv = bias[cc];
            float v[4];
            #pragma unroll
            for (int r = 0; r < 4; ++r) {
                const int rr = orow + mf * 16 + r;
                v[r] = acc[mf][nf][r];
                if constexpr (BIAS) v[r] += bv;
                if constexpr (RELU) v[r] = fmaxf(v[r], 0.f);
                if constexpr (RESMODE == 1)
                    v[r] += ((const float*)resv)[(size_t)rr * ldc + cc];
                if constexpr (RESMODE == 2)
                    v[r] += bf2f(((const unsigned short*)resv)[(size_t)rr * ldc + cc]);
                if constexpr (OUTF32) ((float*)Cv)[(size_t)rr * ldc + cc] = v[r];
            }
            if constexpr (!OUTF32) {
                const unsigned u01 = cvtpk(v[0], v[1]);
                const unsigned u23 = cvtpk(v[2], v[3]);
                unsigned short* cp = (unsigned short*)Cv + (size_t)(orow + mf * 16) * ldc + cc;
                cp[0]                 = (unsigned short)u01;
                cp[(size_t)ldc]       = (unsigned short)(u01 >> 16);
                cp[(size_t)ldc * 2]   = (unsigned short)u23;
                cp[(size_t)ldc * 3]   = (unsigned short)(u23 >> 16);
            }
        }
    }
}

// ---------------------------------------------------------------------------
// Flash attention (r15): swapped QK^T, 32x32x16 MFMA, in-register P.
// 8 waves x 32 q-rows, 512 blocks, KV tiles of 64 double-buffered (single
// barrier/tile). Lane owns q = lane&31; h = lane>>5 is the kv half.
// Hoisted zero-C for QK; cross-half pmax combine only in the rare rescale
// branch; per-lane lsum + final permlane combine.
// ---------------------------------------------------------------------------
__global__ __launch_bounds__(512, 4)
void mfma_attn(unsigned short* __restrict__ qkv)
{
    __shared__ unsigned short Ks[2][64][72];   // K tile [buf][kv][dk]
    __shared__ unsigned short Vt[2][64][72];   // V transposed [buf][dk][kv]

    const int tid  = threadIdx.x;
    const int lane = tid & 63;
    const int w    = tid >> 6;
    const int q32  = lane & 31;      // this lane's q (and kv-row selector)
    const int h    = lane >> 5;      // kv half / k-chunk selector

    // XCD swizzle: 512 blocks = 8 xcd x (8 bh-groups x 8 q-tiles)
    const int bid  = blockIdx.x;
    const int idx  = bid >> 3;
    const int bh   = (bid & 7) * 8 + (idx & 7);
    const int b  = bh >> 3, hd = bh & 7;
    const int s0 = (idx >> 3) << 8;              // q-tile start (256 rows)

    unsigned short* qptr = qkv + ((size_t)(b * SEQ + s0)) * QKVLD + hd * DKH;
    const unsigned short* kbase = qkv + ((size_t)(b * SEQ)) * QKVLD + 512 + hd * DKH;
    const unsigned short* vbase = qkv + ((size_t)(b * SEQ)) * QKVLD + 1024 + hd * DKH;

    // Q fragments (B-operand): lane -> Q[w*32+q32][dk = 16t + 8h .. +7]
    bf16x8 qf[4];
    {
        const unsigned short* qp = qptr + (size_t)(w * 32 + q32) * QKVLD + 8 * h;
        #pragma unroll
        for (int t = 0; t < 4; ++t)
            qf[t] = *(const bf16x8*)(qp + 16 * t);
    }

    // loop-invariant zero C-operand
    f32x16 z16;
    #pragma unroll
    for (int i = 0; i < 16; ++i) z16[i] = 0.f;

    // staging indices
    const int kr = tid >> 3, kc = (tid & 7) << 3;
    const int vr = tid & 63, vc = (tid >> 6) << 3;

    uint4 kreg, vreg;
    auto loadKV = [&](int t0) {
        kreg = *(const uint4*)(kbase + (size_t)(t0 + kr) * QKVLD + kc);
        vreg = *(const uint4*)(vbase + (size_t)(t0 + vr) * QKVLD + vc);
    };
    loadKV(0);

    f32x16 oacc0, oacc1;             // O[q rows][dk = dt*32 + q32]
    #pragma unroll
    for (int i = 0; i < 16; ++i) { oacc0[i] = 0.f; oacc1[i] = 0.f; }
    float m = -INFINITY, lsum = 0.f;

    for (int t0 = 0; t0 < SEQ; t0 += 64) {
        const int cur = (t0 >> 6) & 1;
        *(uint4*)&Ks[cur][kr][kc] = kreg;
        {
            const unsigned short* vu = (const unsigned short*)&vreg;
            #pragma unroll
            for (int j = 0; j < 8; ++j) Vt[cur][vc + j][vr] = vu[j];
        }
        __syncthreads();

        if (t0 + 64 < SEQ) loadKV(t0 + 64);   // prefetch over compute

        // ---- QK^T swapped: D[kv][q]; first MFMA consumes hoisted zero C ----
        f32x16 sa0, sa1;
        __builtin_amdgcn_s_setprio(1);
        {
            const bf16x8 k0 = *(const bf16x8*)&Ks[cur][q32     ][8 * h];
            const bf16x8 k1 = *(const bf16x8*)&Ks[cur][32 + q32][8 * h];
            sa0 = mfma32(k0, qf[0], z16);
            sa1 = mfma32(k1, qf[0], z16);
        }
        #pragma unroll
        for (int t = 1; t < 4; ++t) {
            const bf16x8 k0 = *(const bf16x8*)&Ks[cur][q32     ][16 * t + 8 * h];
            const bf16x8 k1 = *(const bf16x8*)&Ks[cur][32 + q32][16 * t + 8 * h];
            sa0 = mfma32(k0, qf[t], sa0);
            sa1 = mfma32(k1, qf[t], sa1);
        }
        __builtin_amdgcn_s_setprio(0);

        // ---- in-lane softmax (exp2 domain, defer-max) ----
        float pmax = fmaxf(sa0[0], sa1[0]);
        #pragma unroll
        for (int r = 1; r < 16; ++r)
            pmax = fmaxf(pmax, fmaxf(sa0[r], sa1[r]));
        if (__any(pmax > m + 8.f)) {          // rare after first tile
            // cross-half combine only when rescaling
            unsigned xx = fbits(pmax), yy = xx;
            plswap(xx, yy);
            const float partner = (lane < 32) ? bitsf(yy) : bitsf(xx);
            pmax = fmaxf(pmax, partner);
            const float mnew = fmaxf(m, pmax);
            const float alpha = fexp2(m - mnew);   // first tile: 2^-inf = 0
            m = mnew;
            lsum *= alpha;
            #pragma unroll
            for (int r = 0; r < 16; ++r) {
                const int qr = (r & 3) + 8 * (r >> 2) + 4 * h;
                const float ar = __shfl(alpha, qr, 64);
                oacc0[r] *= ar;
                oacc1[r] *= ar;
            }
        }
        // exp2 in place + lazy per-lane sum
        #pragma unroll
        for (int r = 0; r < 16; ++r) {
            sa0[r] = fexp2(sa0[r] - m);
            sa1[r] = fexp2(sa1[r] - m);
            lsum += sa0[r] + sa1[r];
        }

        // ---- pack P to PV A-frags (cvt_pk + permlane32_swap) ----
        bf16x8 pa[4];
        #pragma unroll
        for (int blk = 0; blk < 2; ++blk) {
            const f32x16& p = blk ? sa1 : sa0;
            #pragma unroll
            for (int tt = 0; tt < 2; ++tt) {
                unsigned a0 = cvtpk(p[8 * tt + 0], p[8 * tt + 1]);
                unsigned a1 = cvtpk(p[8 * tt + 2], p[8 * tt + 3]);
                unsigned b0 = cvtpk(p[8 * tt + 4], p[8 * tt + 5]);
                unsigned b1 = cvtpk(p[8 * tt + 6], p[8 * tt + 7]);
                plswap(a0, b0);
                plswap(a1, b1);
                union { uint4 u; bf16x8 v; } cvt;
                cvt.u.x = a0; cvt.u.y = a1; cvt.u.z = b0; cvt.u.w = b1;
                pa[blk * 2 + tt] = cvt.v;
            }
        }

        // ---- O += P V  (B = V from plain-transposed LDS) ----
        __builtin_amdgcn_s_setprio(1);
        #pragma unroll
        for (int ttg = 0; ttg < 4; ++ttg) {    // kv 16-chunks
            const bf16x8 vf0 = *(const bf16x8*)&Vt[cur][q32     ][16 * ttg + 8 * h];
            const bf16x8 vf1 = *(const bf16x8*)&Vt[cur][32 + q32][16 * ttg + 8 * h];
            oacc0 = mfma32(pa[ttg], vf0, oacc0);
            oacc1 = mfma32(pa[ttg], vf1, oacc1);
        }
        __builtin_amdgcn_s_setprio(0);
    }

    // ---- final: pair-combine row sums, normalize, write O in place ----
    float ltot;
    {
        unsigned x = fbits(lsum), y = x;
        plswap(x, y);
        const float partner = (lane < 32) ? bitsf(y) : bitsf(x);
        ltot = lsum + partner;                // symmetric: full row sum for q
    }
    const float inv = 1.f / ltot;
    #pragma unroll
    for (int r = 0; r < 16; ++r) {
        const int qr = (r & 3) + 8 * (r >> 2) + 4 * h;
        const float invr = __shfl(inv, qr, 64);
        unsigned short* op = qptr + (size_t)(w * 32 + qr) * QKVLD + q32;
        op[0]  = f2bf(oacc0[r] * invr);
        op[32] = f2bf(oacc1[r] * invr);
    }
}

// ---------------------------------------------------------------------------
// LayerNorm rows of 512; one wave per row. WF32: fp32 out; WB16: bf16 out.
// ---------------------------------------------------------------------------
template<bool WF32, bool WB16>
__global__ __launch_bounds__(256)
void ln_kernel(const float* __restrict__ in, const float* __restrict__ gg,
               const float* __restrict__ bb, float* __restrict__ outf,
               unsigned short* __restrict__ outb)
{
    const int row = blockIdx.x * 4 + (threadIdx.x >> 6);
    const int lane = threadIdx.x & 63;
    const float* p = in + (size_t)row * D_MODEL;

    const float4 a = *(const float4*)(p + lane * 4);
    const float4 c = *(const float4*)(p + 256 + lane * 4);
    float sum = a.x + a.y + a.z + a.w + c.x + c.y + c.z + c.w;
    float sq  = a.x*a.x + a.y*a.y + a.z*a.z + a.w*a.w
              + c.x*c.x + c.y*c.y + c.z*c.z + c.w*c.w;
    #pragma unroll
    for (int msk = 1; msk < 64; msk <<= 1) {
        sum += __shfl_xor(sum, msk, 64);
        sq  += __shfl_xor(sq,  msk, 64);
    }
    const float mean = sum * (1.f / 512.f);
    const float var  = sq * (1.f / 512.f) - mean * mean;
    const float rs   = rsqrtf(var + 1e-5f);

    const float4 g0 = *(const float4*)(gg + lane * 4);
    const float4 g1 = *(const float4*)(gg + 256 + lane * 4);
    const float4 b0 = *(const float4*)(bb + lane * 4);
    const float4 b1 = *(const float4*)(bb + 256 + lane * 4);

    float4 o0, o1;
    o0.x = (a.x - mean) * rs * g0.x + b0.x;
    o0.y = (a.y - mean) * rs * g0.y + b0.y;
    o0.z = (a.z - mean) * rs * g0.z + b0.z;
    o0.w = (a.w - mean) * rs * g0.w + b0.w;
    o1.x = (c.x - mean) * rs * g1.x + b1.x;
    o1.y = (c.y - mean) * rs * g1.y + b1.y;
    o1.z = (c.z - mean) * rs * g1.z + b1.z;
    o1.w = (c.w - mean) * rs * g1.w + b1.w;
    if constexpr (WF32) {
        *(float4*)(outf + (size_t)row * D_MODEL + lane * 4) = o0;
        *(float4*)(outf + (size_t)row * D_MODEL + 256 + lane * 4) = o1;
    }
    if constexpr (WB16) {
        uint2 pa, pb;
        pa.x = cvtpk(o0.x, o0.y);
        pa.y = cvtpk(o0.z, o0.w);
        pb.x = cvtpk(o1.x, o1.y);
        pb.y = cvtpk(o1.z, o1.w);
        *(uint2*)(outb + (size_t)row * D_MODEL + lane * 4) = pa;
        *(uint2*)(outb + (size_t)row * D_MODEL + 256 + lane * 4) = pb;
    }
}

// ---------------------------------------------------------------------------
// fp32 -> bf16 cast, 8 elems/thread
// ---------------------------------------------------------------------------
__global__ __launch_bounds__(256)
void cast_bf16(const float* __restrict__ in, unsigned short* __restrict__ out)
{
    const size_t i = ((size_t)blockIdx.x * 256 + threadIdx.x) * 8;
    const float4 a = *(const float4*)(in + i);
    const float4 b = *(const float4*)(in + i + 4);
    uint4 o;
    o.x = cvtpk(a.x, a.y);
    o.y = cvtpk(a.z, a.w);
    o.z = cvtpk(b.x, b.y);
    o.w = cvtpk(b.z, b.w);
    *(uint4*)(out + i) = o;
}

// ---------------------------------------------------------------------------
// Weight packing: per-head q/k/v weights -> rows 0..511 / 512..1023 /
// 1024..1535 of Wqkv[1536][512] bf16. q scaled by 0.125*log2e (exp2 softmax).
// ---------------------------------------------------------------------------
__global__ __launch_bounds__(256)
void pack_qkv(const float* __restrict__ wq, const float* __restrict__ wk,
              const float* __restrict__ wv, unsigned short* __restrict__ Wqkv)
{
    const int idx = blockIdx.x * 256 + threadIdx.x;   // n*512 + d, n in 0..511
    const int n = idx >> 9, d = idx & 511;
    const int h = n >> 6, c = n & 63;
    const size_t src = ((size_t)h * 512 + d) * 64 + c;
    Wqkv[idx]                 = f2bf(wq[src] * 0.18033688f);  // 0.125 * log2(e)
    Wqkv[idx + 512 * 512]     = f2bf(wk[src]);
    Wqkv[idx + 2 * 512 * 512] = f2bf(wv[src]);
}

// LDS-tiled transpose-cast: in fp32 [K][N] -> out bf16 [N][K], 32x32 tiles.
__global__ __launch_bounds__(256)
void pack_t(const float* __restrict__ in, unsigned short* __restrict__ out,
            int K, int N)
{
    __shared__ float t[32][33];
    const int kb = blockIdx.x << 5, nb = blockIdx.y << 5;
    const int c = threadIdx.x & 31, r0 = threadIdx.x >> 5;   // 8 row-groups
    #pragma unroll
    for (int j = 0; j < 32; j += 8)
        t[r0 + j][c] = in[(size_t)(kb + r0 + j) * N + nb + c];
    __syncthreads();
    #pragma unroll
    for (int j = 0; j < 32; j += 8)
        out[(size_t)(nb + r0 + j) * K + kb + c] = f2bf(t[c][r0 + j]);
}

// ---------------------------------------------------------------------------
extern "C" void kernel_launch(void* const* d_in, const int* in_sizes, int n_in,
                              void* d_out, int out_size, void* d_ws, size_t ws_size,
                              hipStream_t stream)
{
    (void)in_sizes; (void)n_in; (void)out_size;

    const float* x    = (const float*)d_in[0];
    const float* wq   = (const float*)d_in[1];
    const float* wk   = (const float*)d_in[2];
    const float* wv   = (const float*)d_in[3];
    const float* wo   = (const float*)d_in[4];
    const float* w1   = (const float*)d_in[5];
    const float* b1   = (const float*)d_in[6];
    const float* w2   = (const float*)d_in[7];
    const float* b2   = (const float*)d_in[8];
    const float* ln1g = (const float*)d_in[9];
    const float* ln1b = (const float*)d_in[10];
    const float* ln2g = (const float*)d_in[11];
    const float* ln2b = (const float*)d_in[12];
    float* out = (float*)d_out;

    // ---- workspace layout (bytes), fixed part ~90.2 MB ----
    const size_t QKV_BYTES = (size_t)MROWS * QKVLD * 2;      // 50.33 MB
    const size_t Y_BYTES   = (size_t)MROWS * D_MODEL * 4;    // 33.55 MB
    unsigned char* base = (unsigned char*)d_ws;
    unsigned short* qkv  = (unsigned short*)(base);
    float*          y    = (float*)(base + QKV_BYTES);
    unsigned short* Wqkv = (unsigned short*)(base + QKV_BYTES + Y_BYTES);
    unsigned short* wo_t = Wqkv + 3 * 512 * 512;
    unsigned short* w1_t = wo_t + 512 * 512;
    unsigned short* w2_t = w1_t + 2048 * 512;
    unsigned short* hid  = w2_t + 2048 * 512;

    const size_t hid_off = (size_t)((unsigned char*)hid - base);
    const size_t avail = (ws_size > hid_off) ? (ws_size - hid_off) : 0;
    int chunk = (int)(avail / ((size_t)DFF * 2));
    chunk &= ~127;
    if (chunk > MROWS) chunk = MROWS;
    if (chunk < 128)   chunk = 128;

    float* y2 = (float*)qkv;                       // qkv dead after WO GEMM
    unsigned short* xb  = (unsigned short*)d_out;  // bf16 x until LN1
    unsigned short* x1b = (unsigned short*)d_out;  // then bf16 x1

    // ---- weight packing + x cast ----
    pack_qkv<<<1024, 256, 0, stream>>>(wq, wk, wv, Wqkv);
    pack_t<<<dim3(16, 16), 256, 0, stream>>>(wo, wo_t, 512, 512);
    pack_t<<<dim3(16, 64), 256, 0, stream>>>(w1, w1_t, 512, 2048);
    pack_t<<<dim3(64, 16), 256, 0, stream>>>(w2, w2_t, 2048, 512);
    cast_bf16<<<(MROWS * D_MODEL) / (256 * 8), 256, 0, stream>>>(x, xb);

    const dim3 blk(256);

    // 1) fused q|k|v projection: xb[M][512] @ Wqkv^T -> qkv[M][1536]
    mfma_gemm<false, false, 0, false>
        <<<dim3(12, MROWS / 128), blk, 0, stream>>>(xb, Wqkv, nullptr, nullptr,
                                                    qkv, 512, 512, QKVLD);

    // 2) flash attention (O bf16 in place over q section), XCD-swizzled grid
    mfma_attn<<<dim3(512), dim3(512), 0, stream>>>(qkv);

    // 3) y = O @ wo + x   (fp32 out, fp32 residual)
    mfma_gemm<false, false, 1, true>
        <<<dim3(4, MROWS / 128), blk, 0, stream>>>(qkv, wo_t, nullptr, x, y,
                                                   512, QKVLD, 512);

    // 4) x1 = LN1(y): bf16 only into d_out (FFN2 residual reads bf16)
    ln_kernel<false, true><<<MROWS / 4, blk, 0, stream>>>(y, ln1g, ln1b,
                                                          nullptr, x1b);

    // 5+6) FFN, chunked over rows (chunk multiple of 128)
    for (int r0 = 0; r0 < MROWS; r0 += chunk) {
        const int rows = (r0 + chunk <= MROWS) ? chunk : (MROWS - r0);
        mfma_gemm<true, true, 0, false>
            <<<dim3(DFF / 128, rows / 128), blk, 0, stream>>>(
                x1b + (size_t)r0 * D_MODEL, w1_t, b1, nullptr, hid,
                512, 512, DFF);
        mfma_gemm<true, false, 2, true>
            <<<dim3(4, rows / 128), blk, 0, stream>>>(
                hid, w2_t, b2, x1b + (size_t)r0 * D_MODEL,
                y2 + (size_t)r0 * D_MODEL, DFF, DFF, 512);
    }

    // 7) out = LN2(y2)
    ln_kernel<true, false><<<MROWS / 4, blk, 0, stream>>>(y2, ln2g, ln2b,
                                                          out, nullptr);
}

// Round 18
// 280.629 us; speedup vs baseline: 1.0856x; 1.0421x over previous
//
#include <hip/hip_runtime.h>
#include <hip/hip_bf16.h>
#include <math.h>

// ---------------------------------------------------------------------------
// EncoderLayer, bf16-MFMA mixed precision for MI355X (gfx950).
// B=8, S=2048, D=512, H=8, DK=64, DFF=2048, M=16384.
// Round-18 (on the validated r15/r17 plateau; no sync-structure changes):
//  (1) y and y2 intermediates stored bf16 (tolerance is 0.108, we run 0.031
//      -> 3x headroom): WO/FFN2 epilogues write bf16, LN1/LN2 read bf16.
//      Saves ~67 MB HBM traffic (~10us).
//  (2) prologue fused into ONE prep_all kernel (cast + qkv pack + 3x
//      transpose-pack), removing 4 launch gaps.
// GEMM template, attention, LN math, swizzles byte-identical to r17.
// ---------------------------------------------------------------------------

#define D_MODEL 512
#define NHEAD   8
#define DKH     64
#define SEQ     2048
#define BATCH   8
#define DFF     2048
#define MROWS   (BATCH * SEQ)          // 16384
#define QKVLD   1536                   // fused q|k|v row stride

typedef __bf16 bf16x8 __attribute__((ext_vector_type(8)));
typedef float  f32x4  __attribute__((ext_vector_type(4)));
typedef float  f32x16 __attribute__((ext_vector_type(16)));

__device__ __forceinline__ unsigned short f2bf(float f) {
    union { float f; unsigned u; } v; v.f = f;
    return (unsigned short)((v.u + 0x7FFFu + ((v.u >> 16) & 1u)) >> 16);
}

__device__ __forceinline__ float bf2f(unsigned short u) {
    union { unsigned u; float f; } v; v.u = (unsigned)u << 16;
    return v.f;
}

__device__ __forceinline__ unsigned cvtpk(float a, float b) {   // bf16(a)|bf16(b)<<16
    unsigned r;
    asm("v_cvt_pk_bf16_f32 %0, %1, %2" : "=v"(r) : "v"(a), "v"(b));
    return r;
}

__device__ __forceinline__ float fexp2(float x) {   // raw v_exp_f32 (2^x)
    float r; asm("v_exp_f32 %0, %1" : "=v"(r) : "v"(x)); return r;
}

// v_permlane32_swap_b32: x<-[x(0:31)|y(0:31)], y<-[x(32:63)|y(32:63)]
__device__ __forceinline__ void plswap(unsigned& x, unsigned& y) {
    asm volatile("v_permlane32_swap_b32 %0, %1" : "+v"(x), "+v"(y));
}

__device__ __forceinline__ unsigned fbits(float f) {
    union { float f; unsigned u; } v; v.f = f; return v.u;
}
__device__ __forceinline__ float bitsf(unsigned u) {
    union { unsigned u; float f; } v; v.u = u; return v.f;
}

__device__ __forceinline__ f32x4 mfma16(bf16x8 a, bf16x8 b, f32x4 c) {
    return __builtin_amdgcn_mfma_f32_16x16x32_bf16(a, b, c, 0, 0, 0);
}
__device__ __forceinline__ f32x16 mfma32(bf16x8 a, bf16x8 b, f32x16 c) {
    return __builtin_amdgcn_mfma_f32_32x32x16_bf16(a, b, c, 0, 0, 0);
}

// async global -> LDS, 16 B per lane; lds base must be wave-uniform
__device__ __forceinline__ void gld_lds16(const unsigned short* g, unsigned short* l) {
    __builtin_amdgcn_global_load_lds(
        (const __attribute__((address_space(1))) unsigned int*)g,
        (__attribute__((address_space(3))) unsigned int*)l, 16, 0, 0);
}

// ---------------------------------------------------------------------------
// bf16 MFMA GEMM (proven 128x128 template): BK=32, 256 threads = 4 waves,
// each wave a 64x64 quadrant (4x4 fragments of 16x16x32). Double-buffered
// global_load_lds staging (issue next tile before MFMAs of current; one
// barrier per K-step). RESMODE: 0 none, 1 fp32, 2 bf16.
// ---------------------------------------------------------------------------
template<bool BIAS, bool RELU, int RESMODE, bool OUTF32>
__global__ __launch_bounds__(256)
void mfma_gemm(const unsigned short* __restrict__ Av,
               const unsigned short* __restrict__ Bt,
               const float* __restrict__ bias, const void* __restrict__ resv,
               void* __restrict__ Cv, int Kdim, int lda, int ldc)
{
    __shared__ unsigned short As[2][128][32];
    __shared__ unsigned short Bs[2][128][32];

    const int tid  = threadIdx.x;
    const int lane = tid & 63;
    const int w    = tid >> 6;
    const int mq   = (w >> 1) << 6;
    const int nq   = (w & 1) << 6;
    const int lrow = lane & 15;
    const int g    = lane >> 4;
    const int lk   = g << 3;

    const int row0 = blockIdx.y << 7;
    const int col0 = blockIdx.x << 7;

    const int c0   = w << 5;
    const int srow = lane >> 2;
    const int scol = (lane & 3) << 3;
    const size_t aoff = (size_t)(row0 + c0 + srow) * lda  + scol;
    const size_t boff = (size_t)(col0 + c0 + srow) * Kdim + scol;

    auto stage = [&](int buf, int kt) {
        gld_lds16(Av + aoff + kt,                        &As[buf][c0     ][0]);
        gld_lds16(Av + aoff + (size_t)16 * lda  + kt,    &As[buf][c0 + 16][0]);
        gld_lds16(Bt + boff + kt,                        &Bs[buf][c0     ][0]);
        gld_lds16(Bt + boff + (size_t)16 * Kdim + kt,    &Bs[buf][c0 + 16][0]);
    };

    const f32x4 zero = {0.f, 0.f, 0.f, 0.f};
    f32x4 acc[4][4];
    #pragma unroll
    for (int i = 0; i < 4; ++i)
        #pragma unroll
        for (int j = 0; j < 4; ++j) acc[i][j] = zero;

    stage(0, 0);
    __syncthreads();

    int cur = 0;
    for (int kt = 0; kt < Kdim; kt += 32) {
        if (kt + 32 < Kdim) stage(cur ^ 1, kt + 32);

        bf16x8 af[4], bfv[4];
        #pragma unroll
        for (int mf = 0; mf < 4; ++mf)
            af[mf] = *(const bf16x8*)&As[cur][mq + mf * 16 + lrow][lk];
        #pragma unroll
        for (int nf = 0; nf < 4; ++nf)
            bfv[nf] = *(const bf16x8*)&Bs[cur][nq + nf * 16 + lrow][lk];
        #pragma unroll
        for (int mf = 0; mf < 4; ++mf)
            #pragma unroll
            for (int nf = 0; nf < 4; ++nf)
                acc[mf][nf] = mfma16(af[mf], bfv[nf], acc[mf][nf]);

        __syncthreads();
        cur ^= 1;
    }

    const int orow = row0 + mq + g * 4;
    const int ocol = col0 + nq + lrow;
    #pragma unroll
    for (int mf = 0; mf < 4; ++mf) {
        #pragma unroll
        for (int nf = 0; nf < 4; ++nf) {
            const int cc = ocol + nf * 16;
            float bv = 0.f;
            if constexpr (BIAS) bv = bias[cc];
            float v[4];
            #pragma unroll
            for (int r = 0; r < 4; ++r) {
                const int rr = orow + mf * 16 + r;
                v[r] = acc[mf][nf][r];
                if constexpr (BIAS) v[r] += bv;
                if constexpr (RELU) v[r] = fmaxf(v[r], 0.f);
                if constexpr (RESMODE == 1)
                    v[r] += ((const float*)resv)[(size_t)rr * ldc + cc];
                if constexpr (RESMODE == 2)
                    v[r] += bf2f(((const unsigned short*)resv)[(size_t)rr * ldc + cc]);
                if constexpr (OUTF32) ((float*)Cv)[(size_t)rr * ldc + cc] = v[r];
            }
            if constexpr (!OUTF32) {
                const unsigned u01 = cvtpk(v[0], v[1]);
                const unsigned u23 = cvtpk(v[2], v[3]);
                unsigned short* cp = (unsigned short*)Cv + (size_t)(orow + mf * 16) * ldc + cc;
                cp[0]                 = (unsigned short)u01;
                cp[(size_t)ldc]       = (unsigned short)(u01 >> 16);
                cp[(size_t)ldc * 2]   = (unsigned short)u23;
                cp[(size_t)ldc * 3]   = (unsigned short)(u23 >> 16);
            }
        }
    }
}

// ---------------------------------------------------------------------------
// Flash attention (r15, unchanged): swapped QK^T, 32x32x16 MFMA, in-register
// P. 8 waves x 32 q-rows, 512 blocks, KV tiles of 64 double-buffered (single
// barrier/tile). Lane owns q = lane&31; h = lane>>5 is the kv half.
// ---------------------------------------------------------------------------
__global__ __launch_bounds__(512, 4)
void mfma_attn(unsigned short* __restrict__ qkv)
{
    __shared__ unsigned short Ks[2][64][72];   // K tile [buf][kv][dk]
    __shared__ unsigned short Vt[2][64][72];   // V transposed [buf][dk][kv]

    const int tid  = threadIdx.x;
    const int lane = tid & 63;
    const int w    = tid >> 6;
    const int q32  = lane & 31;
    const int h    = lane >> 5;

    const int bid  = blockIdx.x;
    const int idx  = bid >> 3;
    const int bh   = (bid & 7) * 8 + (idx & 7);
    const int b  = bh >> 3, hd = bh & 7;
    const int s0 = (idx >> 3) << 8;

    unsigned short* qptr = qkv + ((size_t)(b * SEQ + s0)) * QKVLD + hd * DKH;
    const unsigned short* kbase = qkv + ((size_t)(b * SEQ)) * QKVLD + 512 + hd * DKH;
    const unsigned short* vbase = qkv + ((size_t)(b * SEQ)) * QKVLD + 1024 + hd * DKH;

    bf16x8 qf[4];
    {
        const unsigned short* qp = qptr + (size_t)(w * 32 + q32) * QKVLD + 8 * h;
        #pragma unroll
        for (int t = 0; t < 4; ++t)
            qf[t] = *(const bf16x8*)(qp + 16 * t);
    }

    f32x16 z16;
    #pragma unroll
    for (int i = 0; i < 16; ++i) z16[i] = 0.f;

    const int kr = tid >> 3, kc = (tid & 7) << 3;
    const int vr = tid & 63, vc = (tid >> 6) << 3;

    uint4 kreg, vreg;
    auto loadKV = [&](int t0) {
        kreg = *(const uint4*)(kbase + (size_t)(t0 + kr) * QKVLD + kc);
        vreg = *(const uint4*)(vbase + (size_t)(t0 + vr) * QKVLD + vc);
    };
    loadKV(0);

    f32x16 oacc0, oacc1;
    #pragma unroll
    for (int i = 0; i < 16; ++i) { oacc0[i] = 0.f; oacc1[i] = 0.f; }
    float m = -INFINITY, lsum = 0.f;

    for (int t0 = 0; t0 < SEQ; t0 += 64) {
        const int cur = (t0 >> 6) & 1;
        *(uint4*)&Ks[cur][kr][kc] = kreg;
        {
            const unsigned short* vu = (const unsigned short*)&vreg;
            #pragma unroll
            for (int j = 0; j < 8; ++j) Vt[cur][vc + j][vr] = vu[j];
        }
        __syncthreads();

        if (t0 + 64 < SEQ) loadKV(t0 + 64);

        f32x16 sa0, sa1;
        __builtin_amdgcn_s_setprio(1);
        {
            const bf16x8 k0 = *(const bf16x8*)&Ks[cur][q32     ][8 * h];
            const bf16x8 k1 = *(const bf16x8*)&Ks[cur][32 + q32][8 * h];
            sa0 = mfma32(k0, qf[0], z16);
            sa1 = mfma32(k1, qf[0], z16);
        }
        #pragma unroll
        for (int t = 1; t < 4; ++t) {
            const bf16x8 k0 = *(const bf16x8*)&Ks[cur][q32     ][16 * t + 8 * h];
            const bf16x8 k1 = *(const bf16x8*)&Ks[cur][32 + q32][16 * t + 8 * h];
            sa0 = mfma32(k0, qf[t], sa0);
            sa1 = mfma32(k1, qf[t], sa1);
        }
        __builtin_amdgcn_s_setprio(0);

        float pmax = fmaxf(sa0[0], sa1[0]);
        #pragma unroll
        for (int r = 1; r < 16; ++r)
            pmax = fmaxf(pmax, fmaxf(sa0[r], sa1[r]));
        if (__any(pmax > m + 8.f)) {
            unsigned xx = fbits(pmax), yy = xx;
            plswap(xx, yy);
            const float partner = (lane < 32) ? bitsf(yy) : bitsf(xx);
            pmax = fmaxf(pmax, partner);
            const float mnew = fmaxf(m, pmax);
            const float alpha = fexp2(m - mnew);
            m = mnew;
            lsum *= alpha;
            #pragma unroll
            for (int r = 0; r < 16; ++r) {
                const int qr = (r & 3) + 8 * (r >> 2) + 4 * h;
                const float ar = __shfl(alpha, qr, 64);
                oacc0[r] *= ar;
                oacc1[r] *= ar;
            }
        }
        #pragma unroll
        for (int r = 0; r < 16; ++r) {
            sa0[r] = fexp2(sa0[r] - m);
            sa1[r] = fexp2(sa1[r] - m);
            lsum += sa0[r] + sa1[r];
        }

        bf16x8 pa[4];
        #pragma unroll
        for (int blk = 0; blk < 2; ++blk) {
            const f32x16& p = blk ? sa1 : sa0;
            #pragma unroll
            for (int tt = 0; tt < 2; ++tt) {
                unsigned a0 = cvtpk(p[8 * tt + 0], p[8 * tt + 1]);
                unsigned a1 = cvtpk(p[8 * tt + 2], p[8 * tt + 3]);
                unsigned b0 = cvtpk(p[8 * tt + 4], p[8 * tt + 5]);
                unsigned b1 = cvtpk(p[8 * tt + 6], p[8 * tt + 7]);
                plswap(a0, b0);
                plswap(a1, b1);
                union { uint4 u; bf16x8 v; } cvt;
                cvt.u.x = a0; cvt.u.y = a1; cvt.u.z = b0; cvt.u.w = b1;
                pa[blk * 2 + tt] = cvt.v;
            }
        }

        __builtin_amdgcn_s_setprio(1);
        #pragma unroll
        for (int ttg = 0; ttg < 4; ++ttg) {
            const bf16x8 vf0 = *(const bf16x8*)&Vt[cur][q32     ][16 * ttg + 8 * h];
            const bf16x8 vf1 = *(const bf16x8*)&Vt[cur][32 + q32][16 * ttg + 8 * h];
            oacc0 = mfma32(pa[ttg], vf0, oacc0);
            oacc1 = mfma32(pa[ttg], vf1, oacc1);
        }
        __builtin_amdgcn_s_setprio(0);
    }

    float ltot;
    {
        unsigned x = fbits(lsum), y = x;
        plswap(x, y);
        const float partner = (lane < 32) ? bitsf(y) : bitsf(x);
        ltot = lsum + partner;
    }
    const float inv = 1.f / ltot;
    #pragma unroll
    for (int r = 0; r < 16; ++r) {
        const int qr = (r & 3) + 8 * (r >> 2) + 4 * h;
        const float invr = __shfl(inv, qr, 64);
        unsigned short* op = qptr + (size_t)(w * 32 + qr) * QKVLD + q32;
        op[0]  = f2bf(oacc0[r] * invr);
        op[32] = f2bf(oacc1[r] * invr);
    }
}

// ---------------------------------------------------------------------------
// LayerNorm rows of 512; one wave per row.
// INF32: fp32 input else bf16. WF32: fp32 out; WB16: bf16 out.
// ---------------------------------------------------------------------------
template<bool INF32, bool WF32, bool WB16>
__global__ __launch_bounds__(256)
void ln_kernel(const void* __restrict__ inv_, const float* __restrict__ gg,
               const float* __restrict__ bb, float* __restrict__ outf,
               unsigned short* __restrict__ outb)
{
    const int row = blockIdx.x * 4 + (threadIdx.x >> 6);
    const int lane = threadIdx.x & 63;

    float4 a, c;
    if constexpr (INF32) {
        const float* p = (const float*)inv_ + (size_t)row * D_MODEL;
        a = *(const float4*)(p + lane * 4);
        c = *(const float4*)(p + 256 + lane * 4);
    } else {
        const unsigned short* p = (const unsigned short*)inv_ + (size_t)row * D_MODEL;
        const uint2 ua = *(const uint2*)(p + lane * 4);
        const uint2 uc = *(const uint2*)(p + 256 + lane * 4);
        a.x = bf2f((unsigned short)ua.x); a.y = bf2f((unsigned short)(ua.x >> 16));
        a.z = bf2f((unsigned short)ua.y); a.w = bf2f((unsigned short)(ua.y >> 16));
        c.x = bf2f((unsigned short)uc.x); c.y = bf2f((unsigned short)(uc.x >> 16));
        c.z = bf2f((unsigned short)uc.y); c.w = bf2f((unsigned short)(uc.y >> 16));
    }

    float sum = a.x + a.y + a.z + a.w + c.x + c.y + c.z + c.w;
    float sq  = a.x*a.x + a.y*a.y + a.z*a.z + a.w*a.w
              + c.x*c.x + c.y*c.y + c.z*c.z + c.w*c.w;
    #pragma unroll
    for (int msk = 1; msk < 64; msk <<= 1) {
        sum += __shfl_xor(sum, msk, 64);
        sq  += __shfl_xor(sq,  msk, 64);
    }
    const float mean = sum * (1.f / 512.f);
    const float var  = sq * (1.f / 512.f) - mean * mean;
    const float rs   = rsqrtf(var + 1e-5f);

    const float4 g0 = *(const float4*)(gg + lane * 4);
    const float4 g1 = *(const float4*)(gg + 256 + lane * 4);
    const float4 b0 = *(const float4*)(bb + lane * 4);
    const float4 b1 = *(const float4*)(bb + 256 + lane * 4);

    float4 o0, o1;
    o0.x = (a.x - mean) * rs * g0.x + b0.x;
    o0.y = (a.y - mean) * rs * g0.y + b0.y;
    o0.z = (a.z - mean) * rs * g0.z + b0.z;
    o0.w = (a.w - mean) * rs * g0.w + b0.w;
    o1.x = (c.x - mean) * rs * g1.x + b1.x;
    o1.y = (c.y - mean) * rs * g1.y + b1.y;
    o1.z = (c.z - mean) * rs * g1.z + b1.z;
    o1.w = (c.w - mean) * rs * g1.w + b1.w;
    if constexpr (WF32) {
        *(float4*)(outf + (size_t)row * D_MODEL + lane * 4) = o0;
        *(float4*)(outf + (size_t)row * D_MODEL + 256 + lane * 4) = o1;
    }
    if constexpr (WB16) {
        uint2 pa, pb;
        pa.x = cvtpk(o0.x, o0.y);
        pa.y = cvtpk(o0.z, o0.w);
        pb.x = cvtpk(o1.x, o1.y);
        pb.y = cvtpk(o1.z, o1.w);
        *(uint2*)(outb + (size_t)row * D_MODEL + lane * 4) = pa;
        *(uint2*)(outb + (size_t)row * D_MODEL + 256 + lane * 4) = pb;
    }
}

// ---------------------------------------------------------------------------
// Fused prologue: one kernel, 7424 blocks x 256 threads.
//   [0,4096):    cast x fp32 -> xb bf16 (8 elems/thread)
//   [4096,5120): pack_qkv (q scaled by 0.125*log2e)
//   [5120,5376): pack_t wo  (K=512,  N=512)
//   [5376,6400): pack_t w1  (K=512,  N=2048)
//   [6400,7424): pack_t w2  (K=2048, N=512)
// Branches are block-uniform; __syncthreads only in the transpose branch.
// ---------------------------------------------------------------------------
__global__ __launch_bounds__(256)
void prep_all(const float* __restrict__ x,  const float* __restrict__ wq,
              const float* __restrict__ wk, const float* __restrict__ wv,
              const float* __restrict__ wo, const float* __restrict__ w1,
              const float* __restrict__ w2,
              unsigned short* __restrict__ xb, unsigned short* __restrict__ Wqkv,
              unsigned short* __restrict__ wo_t, unsigned short* __restrict__ w1_t,
              unsigned short* __restrict__ w2_t)
{
    __shared__ float t[32][33];
    const int bid = blockIdx.x;

    if (bid < 4096) {                       // cast x -> bf16
        const size_t i = ((size_t)bid * 256 + threadIdx.x) * 8;
        const float4 a = *(const float4*)(x + i);
        const float4 b = *(const float4*)(x + i + 4);
        uint4 o;
        o.x = cvtpk(a.x, a.y);
        o.y = cvtpk(a.z, a.w);
        o.z = cvtpk(b.x, b.y);
        o.w = cvtpk(b.z, b.w);
        *(uint4*)(xb + i) = o;
    } else if (bid < 5120) {                // pack q|k|v weights
        const int idx = (bid - 4096) * 256 + threadIdx.x;   // n*512 + d
        const int n = idx >> 9, d = idx & 511;
        const int h = n >> 6, c = n & 63;
        const size_t src = ((size_t)h * 512 + d) * 64 + c;
        Wqkv[idx]                 = f2bf(wq[src] * 0.18033688f);  // 0.125*log2(e)
        Wqkv[idx + 512 * 512]     = f2bf(wk[src]);
        Wqkv[idx + 2 * 512 * 512] = f2bf(wv[src]);
    } else {                                // LDS-tiled transpose-cast
        const float* in; unsigned short* outp; int K, N, b;
        if (bid < 5376)      { in = wo; outp = wo_t; K = 512;  N = 512;  b = bid - 5120; }
        else if (bid < 6400) { in = w1; outp = w1_t; K = 512;  N = 2048; b = bid - 5376; }
        else                 { in = w2; outp = w2_t; K = 2048; N = 512;  b = bid - 6400; }
        const int gx = K >> 5;
        const int kb = (b % gx) << 5, nb = (b / gx) << 5;
        const int c = threadIdx.x & 31, r0 = threadIdx.x >> 5;
        #pragma unroll
        for (int j = 0; j < 32; j += 8)
            t[r0 + j][c] = in[(size_t)(kb + r0 + j) * N + nb + c];
        __syncthreads();
        #pragma unroll
        for (int j = 0; j < 32; j += 8)
            outp[(size_t)(nb + r0 + j) * K + kb + c] = f2bf(t[c][r0 + j]);
    }
}

// ---------------------------------------------------------------------------
extern "C" void kernel_launch(void* const* d_in, const int* in_sizes, int n_in,
                              void* d_out, int out_size, void* d_ws, size_t ws_size,
                              hipStream_t stream)
{
    (void)in_sizes; (void)n_in; (void)out_size;

    const float* x    = (const float*)d_in[0];
    const float* wq   = (const float*)d_in[1];
    const float* wk   = (const float*)d_in[2];
    const float* wv   = (const float*)d_in[3];
    const float* wo   = (const float*)d_in[4];
    const float* w1   = (const float*)d_in[5];
    const float* b1   = (const float*)d_in[6];
    const float* w2   = (const float*)d_in[7];
    const float* b2   = (const float*)d_in[8];
    const float* ln1g = (const float*)d_in[9];
    const float* ln1b = (const float*)d_in[10];
    const float* ln2g = (const float*)d_in[11];
    const float* ln2b = (const float*)d_in[12];
    float* out = (float*)d_out;

    // ---- workspace layout (bytes); offsets unchanged from r17 ----
    const size_t QKV_BYTES = (size_t)MROWS * QKVLD * 2;      // 50.33 MB
    const size_t Y_BYTES   = (size_t)MROWS * D_MODEL * 4;    // region kept
    unsigned char* base = (unsigned char*)d_ws;
    unsigned short* qkv  = (unsigned short*)(base);
    unsigned short* yb   = (unsigned short*)(base + QKV_BYTES);   // bf16 y
    unsigned short* Wqkv = (unsigned short*)(base + QKV_BYTES + Y_BYTES);
    unsigned short* wo_t = Wqkv + 3 * 512 * 512;
    unsigned short* w1_t = wo_t + 512 * 512;
    unsigned short* w2_t = w1_t + 2048 * 512;
    unsigned short* hid  = w2_t + 2048 * 512;

    const size_t hid_off = (size_t)((unsigned char*)hid - base);
    const size_t avail = (ws_size > hid_off) ? (ws_size - hid_off) : 0;
    int chunk = (int)(avail / ((size_t)DFF * 2));
    chunk &= ~127;
    if (chunk > MROWS) chunk = MROWS;
    if (chunk < 128)   chunk = 128;

    unsigned short* y2b = qkv;                     // qkv dead after WO GEMM
    unsigned short* xb  = (unsigned short*)d_out;  // bf16 x until LN1
    unsigned short* x1b = (unsigned short*)d_out;  // then bf16 x1

    // ---- fused prologue: cast + all weight packing, one launch ----
    prep_all<<<7424, 256, 0, stream>>>(x, wq, wk, wv, wo, w1, w2,
                                       xb, Wqkv, wo_t, w1_t, w2_t);

    const dim3 blk(256);

    // 1) fused q|k|v projection: xb[M][512] @ Wqkv^T -> qkv[M][1536]
    mfma_gemm<false, false, 0, false>
        <<<dim3(12, MROWS / 128), blk, 0, stream>>>(xb, Wqkv, nullptr, nullptr,
                                                    qkv, 512, 512, QKVLD);

    // 2) flash attention (O bf16 in place over q section), XCD-swizzled grid
    mfma_attn<<<dim3(512), dim3(512), 0, stream>>>(qkv);

    // 3) y = O @ wo + x   (bf16 out, fp32 residual)
    mfma_gemm<false, false, 1, false>
        <<<dim3(4, MROWS / 128), blk, 0, stream>>>(qkv, wo_t, nullptr, x, yb,
                                                   512, QKVLD, 512);

    // 4) x1 = LN1(yb): bf16 in -> bf16 out into d_out
    ln_kernel<false, false, true><<<MROWS / 4, blk, 0, stream>>>(
        yb, ln1g, ln1b, nullptr, x1b);

    // 5+6) FFN, chunked over rows (chunk multiple of 128)
    for (int r0 = 0; r0 < MROWS; r0 += chunk) {
        const int rows = (r0 + chunk <= MROWS) ? chunk : (MROWS - r0);
        mfma_gemm<true, true, 0, false>
            <<<dim3(DFF / 128, rows / 128), blk, 0, stream>>>(
                x1b + (size_t)r0 * D_MODEL, w1_t, b1, nullptr, hid,
                512, 512, DFF);
        mfma_gemm<true, false, 2, false>
            <<<dim3(4, rows / 128), blk, 0, stream>>>(
                hid, w2_t, b2, x1b + (size_t)r0 * D_MODEL,
                y2b + (size_t)r0 * D_MODEL, DFF, DFF, 512);
    }

    // 7) out = LN2(y2b): bf16 in -> fp32 out
    ln_kernel<false, true, false><<<MROWS / 4, blk, 0, stream>>>(
        y2b, ln2g, ln2b, out, nullptr);
}